// Round 11
// baseline (150.619 us; speedup 1.0000x reference)
//
#include <hip/hip_runtime.h>
#include <cstdint>
#include <cstddef>

// ---------------------------------------------------------------------------
// GraphTransformerLayer on MI355X (gfx950)
//  - Floyd-Warshall w/ clip(10)  ==  BFS truncated at depth 9 (bitset)
//    R11: gather ILP 4->8, pre-scaled u32 offsets in list, dual accumulators
//  - GEMMs: 64x64 tiles, split-K for N=512 GEMMs (partials summed in LN)
//  - Attention (R10): LDS-staged shared K/V flash structure; in-register
//    softmax (swapped QK^T); cross-z combine x4 on bf16 partials.
// ---------------------------------------------------------------------------

typedef __attribute__((ext_vector_type(8))) short short8;     // 8 x bf16 (4 VGPR)
typedef __attribute__((ext_vector_type(4))) float f32x4;      // MFMA C/D frag

#define N_NODES 2048
#define DMODEL  512
#define NHEAD   8
#define DHEAD   64
#define FFDIM   2048

// ---- workspace layout (bytes) ---------------------------------------------
#define OFF_ADJB   (0)                       // u32 [2048][64]        512 KB
#define OFF_DIST   (0x80000)                 // u8  [2048][2048]      4 MB  (later: f32 partial x1)
#define OFF_XB     (0x480000)                // bf16[2048][512]       2 MB
#define OFF_WQB    (0x680000)                // bf16[512][512]        512 KB
#define OFF_WKB    (0x700000)
#define OFF_WVB    (0x780000)
#define OFF_WOB    (0x800000)
#define OFF_W1B    (0x880000)                // bf16[2048][512]       2 MB
#define OFF_W2B    (0xA80000)                // bf16[512][2048]       2 MB
#define OFF_QM     (0xC80000)                // bf16[2048][512]       2 MB  (later: f32 partial x1 spans QM+KM)
#define OFF_KM     (0xE80000)                // bf16[2048][512]       2 MB
#define OFF_VT     (0x1080000)               // bf16[512][2048]       2 MB  (later: f32 partial x1 spans VT+CTX)
#define OFF_CTX    (0x1280000)               // bf16[2048][512]       2 MB
#define OFF_ATMP   (0x1480000)               // f32 [2048][512]       4 MB
#define OFF_H1     (0x1880000)               // f32 [2048][512]       4 MB
#define OFF_H1B    (0x1C80000)               // bf16[2048][512]       2 MB
#define OFF_MID    (0x1E80000)               // bf16[2048][2048]      8 MB  (earlier: attn partial O bf16 [4][2048][512])
#define OFF_FFN2   (0x2680000)               // f32 [2048][512]       4 MB  (earlier: attn partial ml f32 [4][2048][8][2])
// total 44.5 MB

__device__ __forceinline__ unsigned short f2bf(float f) {
  union { float f; unsigned u; } c; c.f = f;
  unsigned r = c.u + 0x7FFFu + ((c.u >> 16) & 1u);   // RNE
  return (unsigned short)(r >> 16);
}

__device__ __forceinline__ float bf2f(unsigned short u) {
  union { unsigned u; float f; } c; c.u = ((unsigned)u) << 16;
  return c.f;
}

__device__ __forceinline__ uint32_t cvtpk_bf16(float lo, float hi) {
  uint32_t r;
  asm("v_cvt_pk_bf16_f32 %0, %1, %2" : "=v"(r) : "v"(lo), "v"(hi));
  return r;
}

// global -> LDS async, 16B per lane. HW writes LDS at wave-uniform base + lane*16.
typedef const __attribute__((address_space(1))) unsigned int* as1_u32p;
typedef __attribute__((address_space(3))) unsigned int* as3_u32p;
__device__ __forceinline__ void gload_lds16(const void* g, void* l) {
  __builtin_amdgcn_global_load_lds((as1_u32p)g, (as3_u32p)l, 16, 0, 0);
}

// ---------------------------------------------------------------------------
// fused f32 -> bf16 conversion for all 7 arrays (4 elems/thread)
// ---------------------------------------------------------------------------
__global__ void cvt_all_kernel(const float* __restrict__ x,
                               const float* __restrict__ wq, const float* __restrict__ wk,
                               const float* __restrict__ wv, const float* __restrict__ wo,
                               const float* __restrict__ w1, const float* __restrict__ w2,
                               unsigned short* __restrict__ xb,
                               unsigned short* __restrict__ wqb, unsigned short* __restrict__ wkb,
                               unsigned short* __restrict__ wvb, unsigned short* __restrict__ wob,
                               unsigned short* __restrict__ w1b, unsigned short* __restrict__ w2b) {
  int i = blockIdx.x * 256 + threadIdx.x;       // 0 .. 1048575
  const float* src; unsigned short* dst; int off;
  if (i < 262144)      { src = x;  dst = xb;  off = i; }
  else if (i < 327680) { src = wq; dst = wqb; off = i - 262144; }
  else if (i < 393216) { src = wk; dst = wkb; off = i - 327680; }
  else if (i < 458752) { src = wv; dst = wvb; off = i - 393216; }
  else if (i < 524288) { src = wo; dst = wob; off = i - 458752; }
  else if (i < 786432) { src = w1; dst = w1b; off = i - 524288; }
  else                 { src = w2; dst = w2b; off = i - 786432; }
  float4 v = ((const float4*)src)[off];
  unsigned p0 = (unsigned)f2bf(v.x) | ((unsigned)f2bf(v.y) << 16);
  unsigned p1 = (unsigned)f2bf(v.z) | ((unsigned)f2bf(v.w) << 16);
  ((uint2*)dst)[off] = make_uint2(p0, p1);
}

// ---------------------------------------------------------------------------
// adj (f32 0/1) -> row bitsets, u32 [2048][64]
// ---------------------------------------------------------------------------
__global__ void pack_adj_kernel(const float* __restrict__ adj, uint32_t* __restrict__ adjb) {
  int i = blockIdx.x;
  int tid = threadIdx.x, wid = tid >> 6, lane = tid & 63;
  for (int it = 0; it < 8; ++it) {
    int jbase = it * 256 + wid * 64;
    int j = jbase + lane;
    unsigned long long m = __ballot(adj[(size_t)i * 2048 + j] > 0.0f);
    int w32 = jbase >> 5;
    if (lane == 0)  adjb[i * 64 + w32]     = (uint32_t)m;
    if (lane == 32) adjb[i * 64 + w32 + 1] = (uint32_t)(m >> 32);
  }
}

// ---------------------------------------------------------------------------
// BFS truncated at depth 9 -> dist u8 in [0,10].
// One block (4 waves) per source row. Per level: compact frontier into LDS
// as PRE-SCALED byte offsets (node*256), pad to x128 with the source id;
// gather with 8 dwordx4 loads in flight per wave (32 nodes/wave/iter), dual
// OR-accumulators to split the dependency chain.
// ---------------------------------------------------------------------------
__global__ __launch_bounds__(256) void bfs_kernel(const uint32_t* __restrict__ adjb,
                                                  uint8_t* __restrict__ dist) {
  int i = blockIdx.x;
  int tid = threadIdx.x, wid = tid >> 6, lane = tid & 63;

  __shared__ uint32_t list_s[2176];          // byte offsets (node<<8)
  __shared__ uint4 comb_v[4][64];
  __shared__ uint32_t wtot[4];
  const uint32_t* comb_u = (const uint32_t*)comb_v;

  uint32_t adjrow = adjb[i * 64 + lane];
  uint32_t diagm  = (lane == (i >> 5)) ? (1u << (i & 31)) : 0u;
  uint32_t front  = adjrow & ~diagm;          // exactly distance-1 nodes
  uint32_t reach  = front | diagm;
  uint32_t dp0 = front;
  uint32_t dp1 = ~(front | diagm);
  uint32_t dp2 = 0u;
  uint32_t dp3 = dp1;

  // per-lane base: adjb + this lane's 16B word-range within a row
  const char* base_lane = (const char*)adjb + (lane & 15) * 16;

  for (int t = 2; t <= 9; ++t) {
    // --- compact frontier into list_s (pre-scaled offsets) ---
    uint32_t fw = __shfl(front, wid * 16 + (lane >> 2));
    uint32_t fb = (fw >> ((lane & 3) * 8)) & 0xFFu;
    int cnt = __popc(fb);
    int scan = cnt;                          // wave-inclusive scan
    #pragma unroll
    for (int o = 1; o < 64; o <<= 1) {
      int u = __shfl_up(scan, o);
      if (lane >= o) scan += u;
    }
    if (lane == 63) wtot[wid] = (uint32_t)scan;
    __syncthreads();
    int w0 = (int)wtot[0], w1 = (int)wtot[1], w2 = (int)wtot[2], w3 = (int)wtot[3];
    int cnt_total = w0 + w1 + w2 + w3;
    if (cnt_total == 0) break;
    int base0 = (wid > 0 ? w0 : 0) + (wid > 1 ? w1 : 0) + (wid > 2 ? w2 : 0);
    int off = base0 + scan - cnt;            // exclusive offset for this thread
    int nodebase = tid * 8;
    while (fb) {
      int b = __builtin_ctz(fb);
      fb &= fb - 1u;
      list_s[off++] = (uint32_t)(nodebase + b) << 8;
    }
    int padded = (cnt_total + 127) & ~127;
    for (int k = cnt_total + tid; k < padded; k += 256)
      list_s[k] = (uint32_t)i << 8;          // source row: subset of reach
    __syncthreads();

    // --- gather: 8 dwordx4 loads in flight, 32 nodes/wave/iteration ---
    uint4 acc0 = make_uint4(0u, 0u, 0u, 0u);
    uint4 acc1 = make_uint4(0u, 0u, 0u, 0u);
    int lg = lane >> 4;                      // node-group 0..3
    for (int base = wid * 32; base < padded; base += 128) {
      #pragma unroll
      for (int j = 0; j < 8; ++j) {
        uint32_t ofs = list_s[base + j * 4 + lg];
        uint4 v = *(const uint4*)(base_lane + ofs);
        if (j & 1) { acc1.x |= v.x; acc1.y |= v.y; acc1.z |= v.z; acc1.w |= v.w; }
        else       { acc0.x |= v.x; acc0.y |= v.y; acc0.z |= v.z; acc0.w |= v.w; }
      }
    }
    acc0.x |= acc1.x; acc0.y |= acc1.y; acc0.z |= acc1.z; acc0.w |= acc1.w;
    comb_v[wid][lane] = acc0;
    __syncthreads();
    uint32_t orv = 0;
    int idx = (lane >> 2) * 4 + (lane & 3);
    #pragma unroll
    for (int w4 = 0; w4 < 4; ++w4)
      #pragma unroll
      for (int g = 0; g < 4; ++g)
        orv |= comb_u[w4 * 256 + g * 64 + idx];
    uint32_t nreach = reach | orv;
    uint32_t nf = nreach & ~reach;
    dp0 = (dp0 & ~nf) | ((t & 1) ? nf : 0u);
    dp1 = (dp1 & ~nf) | ((t & 2) ? nf : 0u);
    dp2 = (dp2 & ~nf) | ((t & 4) ? nf : 0u);
    dp3 = (dp3 & ~nf) | ((t & 8) ? nf : 0u);
    front = nf;
    reach = nreach;
    __syncthreads();                         // protect list_s/comb for next level
  }

  uint32_t p0 = __shfl(dp0, wid * 16 + (lane >> 2));
  uint32_t p1 = __shfl(dp1, wid * 16 + (lane >> 2));
  uint32_t p2 = __shfl(dp2, wid * 16 + (lane >> 2));
  uint32_t p3 = __shfl(dp3, wid * 16 + (lane >> 2));
  int sh = (lane & 3) * 8;
  uint32_t lo = 0, hi = 0;
  #pragma unroll
  for (int j = 0; j < 4; ++j) {
    int bit = sh + j;
    uint32_t d = ((p0 >> bit) & 1u) | (((p1 >> bit) & 1u) << 1) |
                 (((p2 >> bit) & 1u) << 2) | (((p3 >> bit) & 1u) << 3);
    lo |= d << (8 * j);
  }
  #pragma unroll
  for (int j = 0; j < 4; ++j) {
    int bit = sh + 4 + j;
    uint32_t d = ((p0 >> bit) & 1u) | (((p1 >> bit) & 1u) << 1) |
                 (((p2 >> bit) & 1u) << 2) | (((p3 >> bit) & 1u) << 3);
    hi |= d << (8 * j);
  }
  ((uint2*)(dist + (size_t)i * 2048))[tid] = make_uint2(lo, hi);
}

// ---------------------------------------------------------------------------
// GEMM core: C[64,64] += A[64,kc] * W[64,kc]^T  (bf16 row-major, ld = K)
// ---------------------------------------------------------------------------
__device__ __forceinline__ void gemm_core64(const short* __restrict__ A,
                                            const short* __restrict__ W,
                                            int K, int kstart, int kc,
                                            int am0, int bn0,
                                            f32x4 acc[2][2], char* smem) {
  int tid = threadIdx.x, wid = tid >> 6, lane = tid & 63;
  int c15 = lane & 15, g = lane >> 4;
  int wm = wid >> 1, wn = wid & 1;
  char* As = smem;              // 8 KB
  char* Bs = smem + 8192;       // 8 KB

  for (int kt = kstart; kt < kstart + kc; kt += 64) {
    __syncthreads();   // previous tile's LDS reads done
    #pragma unroll
    for (int i = 0; i < 2; ++i) {
      int c   = i * 256 + tid;
      int row = c >> 3;
      int kg  = (c & 7) ^ (row & 7);
      gload_lds16(A + (size_t)(am0 + row) * K + kt + kg * 8,
                  As + i * 4096 + wid * 1024);
      gload_lds16(W + (size_t)(bn0 + row) * K + kt + kg * 8,
                  Bs + i * 4096 + wid * 1024);
    }
    __syncthreads();   // staging complete (implicit vmcnt(0))
    #pragma unroll
    for (int ks = 0; ks < 2; ++ks) {
      short8 af[2], bfr[2];
      #pragma unroll
      for (int mt = 0; mt < 2; ++mt) {
        int row   = wm * 32 + mt * 16 + c15;
        int chunk = (ks * 4 + g) ^ (row & 7);
        af[mt] = *(const short8*)(As + row * 128 + chunk * 16);
      }
      #pragma unroll
      for (int nt = 0; nt < 2; ++nt) {
        int row   = wn * 32 + nt * 16 + c15;
        int chunk = (ks * 4 + g) ^ (row & 7);
        bfr[nt] = *(const short8*)(Bs + row * 128 + chunk * 16);
      }
      #pragma unroll
      for (int mt = 0; mt < 2; ++mt)
        #pragma unroll
        for (int nt = 0; nt < 2; ++nt)
          acc[mt][nt] = __builtin_amdgcn_mfma_f32_16x16x32_bf16(af[mt], bfr[nt], acc[mt][nt], 0, 0, 0);
    }
  }
}

// MODE 0: QKV (3 weight regions; q,k -> bf16 row-major; v -> bf16 transposed vT[d][n])
// MODE 1: f32 out (+bias iff z==0); split-K partial selected by blockIdx.z
// MODE 2: bf16 out + bias + exact GELU
template <int MODE>
__global__ __launch_bounds__(256) void gemm_kernel(
    const short* __restrict__ A,
    const short* __restrict__ W0, const short* __restrict__ W1, const short* __restrict__ W2,
    const float* __restrict__ b0, const float* __restrict__ b1, const float* __restrict__ b2,
    unsigned short* __restrict__ outq, unsigned short* __restrict__ outk, unsigned short* __restrict__ outv,
    float* __restrict__ of0, float* __restrict__ of1, float* __restrict__ of2, float* __restrict__ of3,
    unsigned short* __restrict__ outb,
    int K, int kc, int ldo) {
  __shared__ __align__(16) char smem[16384];
  int by = blockIdx.y, z = blockIdx.z;
  const short* W; const float* bias; int bn0;
  int region = 0;
  if (MODE == 0) {
    region = by >> 3;
    W    = (region == 0) ? W0 : (region == 1) ? W1 : W2;
    bias = (region == 0) ? b0 : (region == 1) ? b1 : b2;
    bn0  = (by & 7) * 64;
  } else {
    W = W0; bias = b0; bn0 = by * 64;
  }
  int am0 = blockIdx.x * 64;

  f32x4 acc[2][2] = {};
  gemm_core64(A, W, K, z * kc, kc, am0, bn0, acc, smem);

  int tid = threadIdx.x, wid = tid >> 6, lane = tid & 63;
  int c15 = lane & 15, g = lane >> 4;
  int wm = wid >> 1, wn = wid & 1;
  float* of = (MODE == 1) ? ((z == 0) ? of0 : (z == 1) ? of1 : (z == 2) ? of2 : of3) : of0;

  #pragma unroll
  for (int mt = 0; mt < 2; ++mt)
    #pragma unroll
    for (int nt = 0; nt < 2; ++nt)
      #pragma unroll
      for (int r = 0; r < 4; ++r) {
        int row = am0 + wm * 32 + mt * 16 + g * 4 + r;   // D: row=(lane>>4)*4+reg
        int col = bn0 + wn * 32 + nt * 16 + c15;         // D: col=lane&15
        if (MODE == 0) {
          float v = acc[mt][nt][r] + bias[col];
          if (region == 0)      outq[(size_t)row * 512 + col] = f2bf(v);
          else if (region == 1) outk[(size_t)row * 512 + col] = f2bf(v);
          else                  outv[(size_t)col * 2048 + row] = f2bf(v);   // vT[d][n]
        } else if (MODE == 1) {
          float v = acc[mt][nt][r] + ((z == 0) ? bias[col] : 0.0f);
          of[(size_t)row * ldo + col] = v;
        } else {
          float v = acc[mt][nt][r] + bias[col];
          float gv = 0.5f * v * (1.0f + erff(v * 0.70710678118654752f));
          outb[(size_t)row * ldo + col] = f2bf(gv);
        }
      }
}

// ---------------------------------------------------------------------------
// Flash attention R10: LDS-staged shared K/V.
// Block (qt, h, z): q rows [qt*64,+64), head h, KV cols [z*512,+512).
// 4 waves; wave w owns q rows [qt*64+w*16,+16); ALL waves share each staged
// 64-kv tile {K 8KB, V 8KB, dist 4KB} (XOR-swizzled via pre-swizzled global
// source, linear DMA dest). 2-barrier single-buffer loop. Inner loop: NO
// global loads. In-register softmax (swapped QK^T).
// ---------------------------------------------------------------------------
__global__ __launch_bounds__(256, 4) void attn_kernel(
    const short* __restrict__ qm, const short* __restrict__ km,
    const short* __restrict__ vT, const uint8_t* __restrict__ dist,
    const float* __restrict__ semb, unsigned short* __restrict__ po,
    float* __restrict__ pml) {
  int qt = blockIdx.x, h = blockIdx.y, z = blockIdx.z;
  int tid = threadIdx.x, wid = tid >> 6, lane = tid & 63;
  int c15 = lane & 15, g = lane >> 4;

  __shared__ __align__(16) char Ks[8192];    // [64 kv][8 chunk16B] swizzled
  __shared__ __align__(16) char Vs[8192];    // [64 dh][8 chunk16B] swizzled
  __shared__ __align__(16) uint8_t Ds[4096]; // [64 q][4 chunk16B]  swizzled
  __shared__ float semb_s[12];
  if (tid < 11) semb_s[tid] = semb[tid];

  int q0  = qt * 64;             // block's q base
  int wq0 = q0 + wid * 16;       // wave's q base
  int kvz = z * 512;

  // Q as MFMA B-operand: lane (g,c15) holds Q[wq0+c15][ks*32+g*8+j]
  short8 aq[2];
  #pragma unroll
  for (int ks = 0; ks < 2; ++ks)
    aq[ks] = *(const short8*)(qm + (size_t)(wq0 + c15) * 512 + h * 64 + ks * 32 + g * 8);

  // staging indices (this thread handles tile chunks i and i+256)
  int i  = tid;                         // 0..255
  int r0 = i >> 3,        c0 = (i & 7) ^ (r0 & 7);
  int r1 = (256 + i) >> 3, c1 = ((256 + i) & 7) ^ (r1 & 7);
  int dr = i >> 2,        dc = (i & 3) ^ (dr & 3);

  f32x4 o[4] = {};
  float m = -1e30f, l = 0.0f;

  for (int t = 0; t < 8; ++t) {
    int kv0 = kvz + t * 64;

    __syncthreads();   // all waves done reading previous tile
    // stage K (2), V (2), dist (1) -- linear LDS dest, pre-swizzled source
    gload_lds16(km + (size_t)(kv0 + r0) * 512 + h * 64 + c0 * 8, Ks + wid * 1024);
    gload_lds16(km + (size_t)(kv0 + r1) * 512 + h * 64 + c1 * 8, Ks + 4096 + wid * 1024);
    gload_lds16(vT + (size_t)(h * 64 + r0) * 2048 + kv0 + c0 * 8, Vs + wid * 1024);
    gload_lds16(vT + (size_t)(h * 64 + r1) * 2048 + kv0 + c1 * 8, Vs + 4096 + wid * 1024);
    gload_lds16(dist + (size_t)(q0 + dr) * 2048 + kv0 + dc * 16, Ds + wid * 1024);
    __syncthreads();   // staging complete (compiler drains vmcnt before barrier)

    // --- S^T = K Q^T (K frags from LDS) ---
    f32x4 sacc[4] = {};
    __builtin_amdgcn_s_setprio(1);
    #pragma unroll
    for (int nt = 0; nt < 4; ++nt) {
      int row = nt * 16 + c15;
      #pragma unroll
      for (int ks = 0; ks < 2; ++ks) {
        short8 bk = *(const short8*)(Ks + row * 128 + (((ks * 4 + g) ^ (row & 7)) * 16));
        sacc[nt] = __builtin_amdgcn_mfma_f32_16x16x32_bf16(bk, aq[ks], sacc[nt], 0, 0, 0);
      }
    }
    __builtin_amdgcn_s_setprio(0);

    // --- scale + spatial bias (dist from LDS); row max ---
    int drow = wid * 16 + c15;
    float rmax = -1e30f;
    #pragma unroll
    for (int nt = 0; nt < 4; ++nt) {
      uint32_t d32 = *(const uint32_t*)(Ds + drow * 64 + ((nt ^ (drow & 3)) * 16) + g * 4);
      #pragma unroll
      for (int r = 0; r < 4; ++r) {
        float s = sacc[nt][r] * 0.125f + semb_s[(d32 >> (8 * r)) & 0xFFu];
        sacc[nt][r] = s;
        rmax = fmaxf(rmax, s);
      }
    }
    rmax = fmaxf(rmax, __shfl_xor(rmax, 16));
    rmax = fmaxf(rmax, __shfl_xor(rmax, 32));

    // --- online softmax update (per-lane scalars, q = c15); exp in-place ---
    float mn = fmaxf(m, rmax);
    float pscale = __expf(m - mn);
    m = mn;
    float rsum = 0.0f;
    #pragma unroll
    for (int nt = 0; nt < 4; ++nt)
      #pragma unroll
      for (int r = 0; r < 4; ++r) {
        float p = __expf(sacc[nt][r] - m);
        sacc[nt][r] = p;
        rsum += p;
      }
    rsum += __shfl_xor(rsum, 16);
    rsum += __shfl_xor(rsum, 32);
    l = l * pscale + rsum;

    // O rescale: O rows are q=g*4+r -> broadcast pscale from lane (g*4+r)
    float psr[4];
    #pragma unroll
    for (int r = 0; r < 4; ++r) psr[r] = __shfl(pscale, g * 4 + r);
    #pragma unroll
    for (int dt = 0; dt < 4; ++dt)
      #pragma unroll
      for (int r = 0; r < 4; ++r)
        o[dt][r] *= psr[r];

    // --- P -> bf16 + exchange into PV A-frags (two scoped halves) ---
    int src_lo = c15 + (g & 1) * 32;
    int src_hi = src_lo + 16;
    int sel = g >> 1;
    short8 pa[2];
    {
      uint32_t p00 = cvtpk_bf16(sacc[0][0], sacc[0][1]);
      uint32_t p01 = cvtpk_bf16(sacc[0][2], sacc[0][3]);
      uint32_t p10 = cvtpk_bf16(sacc[1][0], sacc[1][1]);
      uint32_t p11 = cvtpk_bf16(sacc[1][2], sacc[1][3]);
      uint32_t a0 = (uint32_t)__shfl((int)p00, src_lo);
      uint32_t a1 = (uint32_t)__shfl((int)p01, src_lo);
      uint32_t a2 = (uint32_t)__shfl((int)p00, src_hi);
      uint32_t a3 = (uint32_t)__shfl((int)p01, src_hi);
      uint32_t b0 = (uint32_t)__shfl((int)p10, src_lo);
      uint32_t b1 = (uint32_t)__shfl((int)p11, src_lo);
      uint32_t b2 = (uint32_t)__shfl((int)p10, src_hi);
      uint32_t b3 = (uint32_t)__shfl((int)p11, src_hi);
      union { short8 s8; uint32_t u[4]; } up;
      up.u[0] = sel ? b0 : a0;
      up.u[1] = sel ? b1 : a1;
      up.u[2] = sel ? b2 : a2;
      up.u[3] = sel ? b3 : a3;
      pa[0] = up.s8;
    }
    {
      uint32_t p00 = cvtpk_bf16(sacc[2][0], sacc[2][1]);
      uint32_t p01 = cvtpk_bf16(sacc[2][2], sacc[2][3]);
      uint32_t p10 = cvtpk_bf16(sacc[3][0], sacc[3][1]);
      uint32_t p11 = cvtpk_bf16(sacc[3][2], sacc[3][3]);
      uint32_t a0 = (uint32_t)__shfl((int)p00, src_lo);
      uint32_t a1 = (uint32_t)__shfl((int)p01, src_lo);
      uint32_t a2 = (uint32_t)__shfl((int)p00, src_hi);
      uint32_t a3 = (uint32_t)__shfl((int)p01, src_hi);
      uint32_t b0 = (uint32_t)__shfl((int)p10, src_lo);
      uint32_t b1 = (uint32_t)__shfl((int)p11, src_lo);
      uint32_t b2 = (uint32_t)__shfl((int)p10, src_hi);
      uint32_t b3 = (uint32_t)__shfl((int)p11, src_hi);
      union { short8 s8; uint32_t u[4]; } up;
      up.u[0] = sel ? b0 : a0;
      up.u[1] = sel ? b1 : a1;
      up.u[2] = sel ? b2 : a2;
      up.u[3] = sel ? b3 : a3;
      pa[1] = up.s8;
    }

    // --- O += P V (V frags from LDS) ---
    __builtin_amdgcn_s_setprio(1);
    #pragma unroll
    for (int dt = 0; dt < 4; ++dt) {
      int row = dt * 16 + c15;
      #pragma unroll
      for (int ks = 0; ks < 2; ++ks) {
        short8 bv = *(const short8*)(Vs + row * 128 + (((ks * 4 + g) ^ (row & 7)) * 16));
        o[dt] = __builtin_amdgcn_mfma_f32_16x16x32_bf16(pa[ks], bv, o[dt], 0, 0, 0);
      }
    }
    __builtin_amdgcn_s_setprio(0);
  }

  // ---- write unnormalized partials (no intra-block combine needed) ----
  #pragma unroll
  for (int dt = 0; dt < 4; ++dt)
    #pragma unroll
    for (int r = 0; r < 4; ++r) {
      int q = wq0 + g * 4 + r;
      po[((size_t)z * 2048 + q) * 512 + h * 64 + dt * 16 + c15] = f2bf(o[dt][r]);
    }
  if (g == 0) {
    int q = wq0 + c15;
    pml[(((size_t)z * 2048 + q) * 8 + h) * 2]     = m;
    pml[(((size_t)z * 2048 + q) * 8 + h) * 2 + 1] = l;
  }
}

// ---------------------------------------------------------------------------
// Cross-chunk attention combine (Z=4): ctx = sum(O_z e_z) / sum(l_z e_z)
// ---------------------------------------------------------------------------
__global__ __launch_bounds__(256) void attn_combine_kernel(
    const unsigned short* __restrict__ po, const float* __restrict__ pml,
    unsigned short* __restrict__ ctx) {
  int q = blockIdx.x, tid = threadIdx.x;
  #pragma unroll
  for (int half = 0; half < 2; ++half) {
    int d = half * 256 + tid;
    int h = d >> 6;
    float mm[4], ll[4];
    float ms = -1e30f;
    #pragma unroll
    for (int zz = 0; zz < 4; ++zz) {
      mm[zz] = pml[(((size_t)zz * 2048 + q) * 8 + h) * 2];
      ll[zz] = pml[(((size_t)zz * 2048 + q) * 8 + h) * 2 + 1];
      ms = fmaxf(ms, mm[zz]);
    }
    float num = 0.0f, den = 0.0f;
    #pragma unroll
    for (int zz = 0; zz < 4; ++zz) {
      float e = __expf(mm[zz] - ms);
      num += bf2f(po[((size_t)zz * 2048 + q) * 512 + d]) * e;
      den += ll[zz] * e;
    }
    ctx[(size_t)q * 512 + d] = f2bf(num / den);
  }
}

// ---------------------------------------------------------------------------
// LayerNorm(a + sum of NP partials) row-wise; optional bf16 copy of output
// ---------------------------------------------------------------------------
template <int NP, bool WB>
__global__ __launch_bounds__(256) void ln_kernel(
    const float* __restrict__ a,
    const float* __restrict__ p0, const float* __restrict__ p1,
    const float* __restrict__ p2, const float* __restrict__ p3,
    const float* __restrict__ w, const float* __restrict__ bb,
    float* __restrict__ out, unsigned short* __restrict__ outb) {
  int row = blockIdx.x, tid = threadIdx.x;
  size_t base = (size_t)row * 512;
  float v0 = a[base + tid]       + p0[base + tid];
  float v1 = a[base + tid + 256] + p0[base + tid + 256];
  if (NP > 1) { v0 += p1[base + tid]; v1 += p1[base + tid + 256]; }
  if (NP > 2) { v0 += p2[base + tid]; v1 += p2[base + tid + 256]; }
  if (NP > 3) { v0 += p3[base + tid]; v1 += p3[base + tid + 256]; }
  float s = v0 + v1, q = v0 * v0 + v1 * v1;
  for (int o = 32; o > 0; o >>= 1) { s += __shfl_down(s, o); q += __shfl_down(q, o); }
  __shared__ float rs[4], rq[4], bc[2];
  int wid = tid >> 6, lane = tid & 63;
  if (lane == 0) { rs[wid] = s; rq[wid] = q; }
  __syncthreads();
  if (tid == 0) {
    float S = rs[0] + rs[1] + rs[2] + rs[3];
    float Q = rq[0] + rq[1] + rq[2] + rq[3];
    float mu = S * (1.0f / 512.0f);
    bc[0] = mu;
    bc[1] = Q * (1.0f / 512.0f) - mu * mu;
  }
  __syncthreads();
  float mu = bc[0], inv = rsqrtf(bc[1] + 1e-5f);
  float o0 = (v0 - mu) * inv * w[tid] + bb[tid];
  float o1 = (v1 - mu) * inv * w[tid + 256] + bb[tid + 256];
  out[base + tid] = o0;
  out[base + tid + 256] = o1;
  if (WB) {
    outb[base + tid] = f2bf(o0);
    outb[base + tid + 256] = f2bf(o1);
  }
}

// ---------------------------------------------------------------------------
extern "C" void kernel_launch(void* const* d_in, const int* in_sizes, int n_in,
                              void* d_out, int out_size, void* d_ws, size_t ws_size,
                              hipStream_t stream) {
  (void)in_sizes; (void)n_in; (void)out_size; (void)ws_size;
  const float* x    = (const float*)d_in[0];
  const float* adj  = (const float*)d_in[1];
  const float* semb = (const float*)d_in[2];
  const float* wq   = (const float*)d_in[3];
  const float* bq   = (const float*)d_in[4];
  const float* wk   = (const float*)d_in[5];
  const float* bk   = (const float*)d_in[6];
  const float* wv   = (const float*)d_in[7];
  const float* bv   = (const float*)d_in[8];
  const float* wo   = (const float*)d_in[9];
  const float* bo   = (const float*)d_in[10];
  const float* ln1w = (const float*)d_in[11];
  const float* ln1b = (const float*)d_in[12];
  const float* w1   = (const float*)d_in[13];
  const float* b1   = (const float*)d_in[14];
  const float* w2   = (const float*)d_in[15];
  const float* b2   = (const float*)d_in[16];
  const float* ln2w = (const float*)d_in[17];
  const float* ln2b = (const float*)d_in[18];
  float* out = (float*)d_out;
  char* ws = (char*)d_ws;

  uint32_t*       adjb = (uint32_t*)(ws + OFF_ADJB);
  uint8_t*        dist = (uint8_t*)(ws + OFF_DIST);
  unsigned short* xb   = (unsigned short*)(ws + OFF_XB);
  unsigned short* wqb  = (unsigned short*)(ws + OFF_WQB);
  unsigned short* wkb  = (unsigned short*)(ws + OFF_WKB);
  unsigned short* wvb  = (unsigned short*)(ws + OFF_WVB);
  unsigned short* wob  = (unsigned short*)(ws + OFF_WOB);
  unsigned short* w1b  = (unsigned short*)(ws + OFF_W1B);
  unsigned short* w2b  = (unsigned short*)(ws + OFF_W2B);
  unsigned short* qm   = (unsigned short*)(ws + OFF_QM);
  unsigned short* km   = (unsigned short*)(ws + OFF_KM);
  unsigned short* vT   = (unsigned short*)(ws + OFF_VT);
  unsigned short* ctx  = (unsigned short*)(ws + OFF_CTX);
  float*          atmp = (float*)(ws + OFF_ATMP);
  float*          h1   = (float*)(ws + OFF_H1);
  unsigned short* h1b  = (unsigned short*)(ws + OFF_H1B);
  unsigned short* mid  = (unsigned short*)(ws + OFF_MID);
  float*          ffn2 = (float*)(ws + OFF_FFN2);
  // reused (liveness-checked) regions:
  unsigned short* po   = (unsigned short*)(ws + OFF_MID); // attn partial O bf16 [4][2048][512] (dead before FFN1 writes mid)
  float* pml   = (float*)(ws + OFF_FFN2);   // attn partial ml f32 [4][2048][8][2] (dead before FFN2 writes)
  float* distf = (float*)(ws + OFF_DIST);   // split-K partial (dist dead after attn)
  float* qmf   = (float*)(ws + OFF_QM);     // split-K partial (spans qm+km, dead after attn)
  float* vtf   = (float*)(ws + OFF_VT);     // split-K partial (spans vT+ctx, dead after out-proj)

  // ---- dtype conversions (fused) ----
  cvt_all_kernel<<<4096, 256, 0, stream>>>(x, wq, wk, wv, wo, w1, w2,
                                           xb, wqb, wkb, wvb, wob, w1b, w2b);

  // ---- spatial distances ----
  pack_adj_kernel<<<2048, 256, 0, stream>>>(adj, adjb);
  bfs_kernel<<<2048, 256, 0, stream>>>(adjb, dist);

  // ---- QKV projection (q,k row-major; v transposed) ----
  gemm_kernel<0><<<dim3(32, 24), 256, 0, stream>>>(
      (const short*)xb, (const short*)wqb, (const short*)wkb, (const short*)wvb,
      bq, bk, bv, qm, km, vT,
      nullptr, nullptr, nullptr, nullptr, nullptr, 512, 512, 512);

  // ---- attention (KV-split x4, LDS-staged shared K/V) + combine ----
  attn_kernel<<<dim3(32, 8, 4), 256, 0, stream>>>(
      (const short*)qm, (const short*)km, (const short*)vT, dist, semb, po, pml);
  attn_combine_kernel<<<2048, 256, 0, stream>>>(po, pml, ctx);

  // ---- output projection (split-K x2) ----
  gemm_kernel<1><<<dim3(32, 8, 2), 256, 0, stream>>>(
      (const short*)ctx, (const short*)wob, nullptr, nullptr,
      bo, nullptr, nullptr, nullptr, nullptr, nullptr,
      atmp, distf, nullptr, nullptr, nullptr, 512, 256, 512);

  // ---- LN1 (x + atmp + distf) ----
  ln_kernel<2, true><<<2048, 256, 0, stream>>>(x, atmp, distf, nullptr, nullptr,
                                               ln1w, ln1b, h1, h1b);

  // ---- FFN1 (GELU -> bf16 mid) ----
  gemm_kernel<2><<<dim3(32, 32), 256, 0, stream>>>(
      (const short*)h1b, (const short*)w1b, nullptr, nullptr,
      b1, nullptr, nullptr, nullptr, nullptr, nullptr,
      nullptr, nullptr, nullptr, nullptr, mid, 512, 512, 2048);

  // ---- FFN2 (split-K x4) ----
  gemm_kernel<1><<<dim3(32, 8, 4), 256, 0, stream>>>(
      (const short*)mid, (const short*)w2b, nullptr, nullptr,
      b2, nullptr, nullptr, nullptr, nullptr, nullptr,
      ffn2, distf, qmf, vtf, nullptr, 2048, 512, 512);

  // ---- LN2 (h1 + 4 partials) -> output ----
  ln_kernel<4, false><<<2048, 256, 0, stream>>>(h1, ffn2, distf, qmf, vtf,
                                                ln2w, ln2b, out, nullptr);
}

// Round 12
// 141.950 us; speedup vs baseline: 1.0611x; 1.0611x over previous
//
#include <hip/hip_runtime.h>
#include <cstdint>
#include <cstddef>

// ---------------------------------------------------------------------------
// GraphTransformerLayer on MI355X (gfx950)
//  - Floyd-Warshall w/ clip(10)  ==  BFS truncated at depth 9 (bitset)
//    R12: BFS reverted to the proven R10 form (R11's 8-deep/u32-list version
//    regressed: LDS bloat + TA-queue saturation). BFS fused with the
//    independent QKV GEMM into ONE heterogeneous launch so gemm MFMA work
//    fills bfs's latency stalls (m114 co-schedule: time ~ max, not sum).
//  - GEMMs: 64x64 tiles, split-K for N=512 GEMMs (partials summed in LN)
//  - Attention (R10): LDS-staged shared K/V flash structure; in-register
//    softmax (swapped QK^T); cross-z combine x4 on bf16 partials.
// ---------------------------------------------------------------------------

typedef __attribute__((ext_vector_type(8))) short short8;     // 8 x bf16 (4 VGPR)
typedef __attribute__((ext_vector_type(4))) float f32x4;      // MFMA C/D frag

#define N_NODES 2048
#define DMODEL  512
#define NHEAD   8
#define DHEAD   64
#define FFDIM   2048

// ---- workspace layout (bytes) ---------------------------------------------
#define OFF_ADJB   (0)                       // u32 [2048][64]        512 KB
#define OFF_DIST   (0x80000)                 // u8  [2048][2048]      4 MB  (later: f32 partial x1)
#define OFF_XB     (0x480000)                // bf16[2048][512]       2 MB
#define OFF_WQB    (0x680000)                // bf16[512][512]        512 KB
#define OFF_WKB    (0x700000)
#define OFF_WVB    (0x780000)
#define OFF_WOB    (0x800000)
#define OFF_W1B    (0x880000)                // bf16[2048][512]       2 MB
#define OFF_W2B    (0xA80000)                // bf16[512][2048]       2 MB
#define OFF_QM     (0xC80000)                // bf16[2048][512]       2 MB  (later: f32 partial x1 spans QM+KM)
#define OFF_KM     (0xE80000)                // bf16[2048][512]       2 MB
#define OFF_VT     (0x1080000)               // bf16[512][2048]       2 MB  (later: f32 partial x1 spans VT+CTX)
#define OFF_CTX    (0x1280000)               // bf16[2048][512]       2 MB
#define OFF_ATMP   (0x1480000)               // f32 [2048][512]       4 MB
#define OFF_H1     (0x1880000)               // f32 [2048][512]       4 MB
#define OFF_H1B    (0x1C80000)               // bf16[2048][512]       2 MB
#define OFF_MID    (0x1E80000)               // bf16[2048][2048]      8 MB  (earlier: attn partial O bf16 [4][2048][512])
#define OFF_FFN2   (0x2680000)               // f32 [2048][512]       4 MB  (earlier: attn partial ml f32 [4][2048][8][2])
// total 44.5 MB

__device__ __forceinline__ unsigned short f2bf(float f) {
  union { float f; unsigned u; } c; c.f = f;
  unsigned r = c.u + 0x7FFFu + ((c.u >> 16) & 1u);   // RNE
  return (unsigned short)(r >> 16);
}

__device__ __forceinline__ float bf2f(unsigned short u) {
  union { unsigned u; float f; } c; c.u = ((unsigned)u) << 16;
  return c.f;
}

__device__ __forceinline__ uint32_t cvtpk_bf16(float lo, float hi) {
  uint32_t r;
  asm("v_cvt_pk_bf16_f32 %0, %1, %2" : "=v"(r) : "v"(lo), "v"(hi));
  return r;
}

// global -> LDS async, 16B per lane. HW writes LDS at wave-uniform base + lane*16.
typedef const __attribute__((address_space(1))) unsigned int* as1_u32p;
typedef __attribute__((address_space(3))) unsigned int* as3_u32p;
__device__ __forceinline__ void gload_lds16(const void* g, void* l) {
  __builtin_amdgcn_global_load_lds((as1_u32p)g, (as3_u32p)l, 16, 0, 0);
}

// ---------------------------------------------------------------------------
// fused f32 -> bf16 conversion for all 7 arrays (4 elems/thread)
// ---------------------------------------------------------------------------
__global__ void cvt_all_kernel(const float* __restrict__ x,
                               const float* __restrict__ wq, const float* __restrict__ wk,
                               const float* __restrict__ wv, const float* __restrict__ wo,
                               const float* __restrict__ w1, const float* __restrict__ w2,
                               unsigned short* __restrict__ xb,
                               unsigned short* __restrict__ wqb, unsigned short* __restrict__ wkb,
                               unsigned short* __restrict__ wvb, unsigned short* __restrict__ wob,
                               unsigned short* __restrict__ w1b, unsigned short* __restrict__ w2b) {
  int i = blockIdx.x * 256 + threadIdx.x;       // 0 .. 1048575
  const float* src; unsigned short* dst; int off;
  if (i < 262144)      { src = x;  dst = xb;  off = i; }
  else if (i < 327680) { src = wq; dst = wqb; off = i - 262144; }
  else if (i < 393216) { src = wk; dst = wkb; off = i - 327680; }
  else if (i < 458752) { src = wv; dst = wvb; off = i - 393216; }
  else if (i < 524288) { src = wo; dst = wob; off = i - 458752; }
  else if (i < 786432) { src = w1; dst = w1b; off = i - 524288; }
  else                 { src = w2; dst = w2b; off = i - 786432; }
  float4 v = ((const float4*)src)[off];
  unsigned p0 = (unsigned)f2bf(v.x) | ((unsigned)f2bf(v.y) << 16);
  unsigned p1 = (unsigned)f2bf(v.z) | ((unsigned)f2bf(v.w) << 16);
  ((uint2*)dst)[off] = make_uint2(p0, p1);
}

// ---------------------------------------------------------------------------
// adj (f32 0/1) -> row bitsets, u32 [2048][64]
// ---------------------------------------------------------------------------
__global__ void pack_adj_kernel(const float* __restrict__ adj, uint32_t* __restrict__ adjb) {
  int i = blockIdx.x;
  int tid = threadIdx.x, wid = tid >> 6, lane = tid & 63;
  for (int it = 0; it < 8; ++it) {
    int jbase = it * 256 + wid * 64;
    int j = jbase + lane;
    unsigned long long m = __ballot(adj[(size_t)i * 2048 + j] > 0.0f);
    int w32 = jbase >> 5;
    if (lane == 0)  adjb[i * 64 + w32]     = (uint32_t)m;
    if (lane == 32) adjb[i * 64 + w32 + 1] = (uint32_t)(m >> 32);
  }
}

// ---------------------------------------------------------------------------
// BFS body (R10-proven): one block (4 waves) per source row; LDS frontier
// list (u16); dwordx4 gather, 4 loads in flight per wave.
// smem carve: comb_v [0,4096) | wtot [4096,4112) | list_s [4112,8336)
// ---------------------------------------------------------------------------
__device__ __forceinline__ void bfs_body(int i, const uint32_t* __restrict__ adjb,
                                         uint8_t* __restrict__ dist, char* smem) {
  int tid = threadIdx.x, wid = tid >> 6, lane = tid & 63;

  uint4* comb_v = (uint4*)smem;                       // [4][64]
  uint32_t* wtot = (uint32_t*)(smem + 4096);          // [4]
  uint16_t* list_s = (uint16_t*)(smem + 4112);        // [2112]
  const uint32_t* comb_u = (const uint32_t*)comb_v;

  uint32_t adjrow = adjb[i * 64 + lane];
  uint32_t diagm  = (lane == (i >> 5)) ? (1u << (i & 31)) : 0u;
  uint32_t front  = adjrow & ~diagm;          // exactly distance-1 nodes
  uint32_t reach  = front | diagm;
  uint32_t dp0 = front;
  uint32_t dp1 = ~(front | diagm);
  uint32_t dp2 = 0u;
  uint32_t dp3 = dp1;

  for (int t = 2; t <= 9; ++t) {
    uint32_t fw = __shfl(front, wid * 16 + (lane >> 2));
    uint32_t fb = (fw >> ((lane & 3) * 8)) & 0xFFu;
    int cnt = __popc(fb);
    int scan = cnt;                          // wave-inclusive scan
    #pragma unroll
    for (int o = 1; o < 64; o <<= 1) {
      int u = __shfl_up(scan, o);
      if (lane >= o) scan += u;
    }
    if (lane == 63) wtot[wid] = (uint32_t)scan;
    __syncthreads();
    int w0 = (int)wtot[0], w1 = (int)wtot[1], w2 = (int)wtot[2], w3 = (int)wtot[3];
    int cnt_total = w0 + w1 + w2 + w3;
    if (cnt_total == 0) break;
    int base0 = (wid > 0 ? w0 : 0) + (wid > 1 ? w1 : 0) + (wid > 2 ? w2 : 0);
    int off = base0 + scan - cnt;            // exclusive offset for this thread
    int nodebase = tid * 8;
    while (fb) {
      int b = __builtin_ctz(fb);
      fb &= fb - 1u;
      list_s[off++] = (uint16_t)(nodebase + b);
    }
    int padded = (cnt_total + 63) & ~63;
    for (int k = cnt_total + tid; k < padded; k += 256)
      list_s[k] = (uint16_t)i;               // source row: subset of reach
    __syncthreads();

    uint4 acc = make_uint4(0u, 0u, 0u, 0u);
    int wsub = (lane & 15) * 4;              // this lane's word range
    for (int base = wid * 16; base < padded; base += 64) {
      #pragma unroll
      for (int j = 0; j < 4; ++j) {
        int node = list_s[base + j * 4 + (lane >> 4)];
        uint4 v = *(const uint4*)(adjb + node * 64 + wsub);
        acc.x |= v.x; acc.y |= v.y; acc.z |= v.z; acc.w |= v.w;
      }
    }
    comb_v[wid * 64 + lane] = acc;
    __syncthreads();
    uint32_t orv = 0;
    int idx = (lane >> 2) * 4 + (lane & 3);
    #pragma unroll
    for (int w4 = 0; w4 < 4; ++w4)
      #pragma unroll
      for (int g = 0; g < 4; ++g)
        orv |= comb_u[w4 * 256 + g * 64 + idx];
    uint32_t nreach = reach | orv;
    uint32_t nf = nreach & ~reach;
    dp0 = (dp0 & ~nf) | ((t & 1) ? nf : 0u);
    dp1 = (dp1 & ~nf) | ((t & 2) ? nf : 0u);
    dp2 = (dp2 & ~nf) | ((t & 4) ? nf : 0u);
    dp3 = (dp3 & ~nf) | ((t & 8) ? nf : 0u);
    front = nf;
    reach = nreach;
    __syncthreads();                         // protect list_s/comb for next level
  }

  uint32_t p0 = __shfl(dp0, wid * 16 + (lane >> 2));
  uint32_t p1 = __shfl(dp1, wid * 16 + (lane >> 2));
  uint32_t p2 = __shfl(dp2, wid * 16 + (lane >> 2));
  uint32_t p3 = __shfl(dp3, wid * 16 + (lane >> 2));
  int sh = (lane & 3) * 8;
  uint32_t lo = 0, hi = 0;
  #pragma unroll
  for (int j = 0; j < 4; ++j) {
    int bit = sh + j;
    uint32_t d = ((p0 >> bit) & 1u) | (((p1 >> bit) & 1u) << 1) |
                 (((p2 >> bit) & 1u) << 2) | (((p3 >> bit) & 1u) << 3);
    lo |= d << (8 * j);
  }
  #pragma unroll
  for (int j = 0; j < 4; ++j) {
    int bit = sh + 4 + j;
    uint32_t d = ((p0 >> bit) & 1u) | (((p1 >> bit) & 1u) << 1) |
                 (((p2 >> bit) & 1u) << 2) | (((p3 >> bit) & 1u) << 3);
    hi |= d << (8 * j);
  }
  ((uint2*)(dist + (size_t)i * 2048))[tid] = make_uint2(lo, hi);
}

// ---------------------------------------------------------------------------
// GEMM core: C[64,64] += A[64,kc] * W[64,kc]^T  (bf16 row-major, ld = K)
// ---------------------------------------------------------------------------
__device__ __forceinline__ void gemm_core64(const short* __restrict__ A,
                                            const short* __restrict__ W,
                                            int K, int kstart, int kc,
                                            int am0, int bn0,
                                            f32x4 acc[2][2], char* smem) {
  int tid = threadIdx.x, wid = tid >> 6, lane = tid & 63;
  int c15 = lane & 15, g = lane >> 4;
  int wm = wid >> 1, wn = wid & 1;
  char* As = smem;              // 8 KB
  char* Bs = smem + 8192;       // 8 KB

  for (int kt = kstart; kt < kstart + kc; kt += 64) {
    __syncthreads();   // previous tile's LDS reads done
    #pragma unroll
    for (int i = 0; i < 2; ++i) {
      int c   = i * 256 + tid;
      int row = c >> 3;
      int kg  = (c & 7) ^ (row & 7);
      gload_lds16(A + (size_t)(am0 + row) * K + kt + kg * 8,
                  As + i * 4096 + wid * 1024);
      gload_lds16(W + (size_t)(bn0 + row) * K + kt + kg * 8,
                  Bs + i * 4096 + wid * 1024);
    }
    __syncthreads();   // staging complete (implicit vmcnt(0))
    #pragma unroll
    for (int ks = 0; ks < 2; ++ks) {
      short8 af[2], bfr[2];
      #pragma unroll
      for (int mt = 0; mt < 2; ++mt) {
        int row   = wm * 32 + mt * 16 + c15;
        int chunk = (ks * 4 + g) ^ (row & 7);
        af[mt] = *(const short8*)(As + row * 128 + chunk * 16);
      }
      #pragma unroll
      for (int nt = 0; nt < 2; ++nt) {
        int row   = wn * 32 + nt * 16 + c15;
        int chunk = (ks * 4 + g) ^ (row & 7);
        bfr[nt] = *(const short8*)(Bs + row * 128 + chunk * 16);
      }
      #pragma unroll
      for (int mt = 0; mt < 2; ++mt)
        #pragma unroll
        for (int nt = 0; nt < 2; ++nt)
          acc[mt][nt] = __builtin_amdgcn_mfma_f32_16x16x32_bf16(af[mt], bfr[nt], acc[mt][nt], 0, 0, 0);
    }
  }
}

// ---------------------------------------------------------------------------
// QKV body (was gemm_kernel<0>): q,k -> bf16 row-major; v -> transposed vT
// ---------------------------------------------------------------------------
__device__ __forceinline__ void qkv_body(int bx, int by,
    const short* __restrict__ A,
    const short* __restrict__ W0, const short* __restrict__ W1, const short* __restrict__ W2,
    const float* __restrict__ b0, const float* __restrict__ b1, const float* __restrict__ b2,
    unsigned short* __restrict__ outq, unsigned short* __restrict__ outk,
    unsigned short* __restrict__ outv, char* smem) {
  int region = by >> 3;
  const short* W    = (region == 0) ? W0 : (region == 1) ? W1 : W2;
  const float* bias = (region == 0) ? b0 : (region == 1) ? b1 : b2;
  int bn0 = (by & 7) * 64;
  int am0 = bx * 64;

  f32x4 acc[2][2] = {};
  gemm_core64(A, W, 512, 0, 512, am0, bn0, acc, smem);

  int tid = threadIdx.x, wid = tid >> 6, lane = tid & 63;
  int c15 = lane & 15, g = lane >> 4;
  int wm = wid >> 1, wn = wid & 1;

  #pragma unroll
  for (int mt = 0; mt < 2; ++mt)
    #pragma unroll
    for (int nt = 0; nt < 2; ++nt)
      #pragma unroll
      for (int r = 0; r < 4; ++r) {
        int row = am0 + wm * 32 + mt * 16 + g * 4 + r;   // D: row=(lane>>4)*4+reg
        int col = bn0 + wn * 32 + nt * 16 + c15;         // D: col=lane&15
        float v = acc[mt][nt][r] + bias[col];
        if (region == 0)      outq[(size_t)row * 512 + col] = f2bf(v);
        else if (region == 1) outk[(size_t)row * 512 + col] = f2bf(v);
        else                  outv[(size_t)col * 2048 + row] = f2bf(v);   // vT[d][n]
      }
}

// ---------------------------------------------------------------------------
// Fused heterogeneous launch: blocks [0,2048) = BFS; [2048,2816) = QKV GEMM.
// Independent work co-scheduled so MFMA fills BFS's latency stalls.
// ---------------------------------------------------------------------------
__global__ __launch_bounds__(256) void bfs_qkv_kernel(
    const uint32_t* __restrict__ adjb, uint8_t* __restrict__ dist,
    const short* __restrict__ xb,
    const short* __restrict__ wqb, const short* __restrict__ wkb, const short* __restrict__ wvb,
    const float* __restrict__ bq, const float* __restrict__ bk, const float* __restrict__ bv,
    unsigned short* __restrict__ qm, unsigned short* __restrict__ km,
    unsigned short* __restrict__ vT) {
  __shared__ __align__(16) char smem[16384];
  int b = blockIdx.x;
  if (b < 2048) {
    bfs_body(b, adjb, dist, smem);
  } else {
    int gidx = b - 2048;                       // 0..767
    qkv_body(gidx & 31, gidx >> 5, xb, wqb, wkb, wvb, bq, bk, bv, qm, km, vT, smem);
  }
}

// MODE 1: f32 out (+bias iff z==0); split-K partial selected by blockIdx.z
// MODE 2: bf16 out + bias + exact GELU
template <int MODE>
__global__ __launch_bounds__(256) void gemm_kernel(
    const short* __restrict__ A,
    const short* __restrict__ W0,
    const float* __restrict__ b0,
    float* __restrict__ of0, float* __restrict__ of1,
    float* __restrict__ of2, float* __restrict__ of3,
    unsigned short* __restrict__ outb,
    int K, int kc, int ldo) {
  __shared__ __align__(16) char smem[16384];
  int by = blockIdx.y, z = blockIdx.z;
  int bn0 = by * 64;
  int am0 = blockIdx.x * 64;

  f32x4 acc[2][2] = {};
  gemm_core64(A, W0, K, z * kc, kc, am0, bn0, acc, smem);

  int tid = threadIdx.x, wid = tid >> 6, lane = tid & 63;
  int c15 = lane & 15, g = lane >> 4;
  int wm = wid >> 1, wn = wid & 1;
  float* of = (z == 0) ? of0 : (z == 1) ? of1 : (z == 2) ? of2 : of3;

  #pragma unroll
  for (int mt = 0; mt < 2; ++mt)
    #pragma unroll
    for (int nt = 0; nt < 2; ++nt)
      #pragma unroll
      for (int r = 0; r < 4; ++r) {
        int row = am0 + wm * 32 + mt * 16 + g * 4 + r;   // D: row=(lane>>4)*4+reg
        int col = bn0 + wn * 32 + nt * 16 + c15;         // D: col=lane&15
        if (MODE == 1) {
          float v = acc[mt][nt][r] + ((z == 0) ? b0[col] : 0.0f);
          of[(size_t)row * ldo + col] = v;
        } else {
          float v = acc[mt][nt][r] + b0[col];
          float gv = 0.5f * v * (1.0f + erff(v * 0.70710678118654752f));
          outb[(size_t)row * ldo + col] = f2bf(gv);
        }
      }
}

// ---------------------------------------------------------------------------
// Flash attention (R10): LDS-staged shared K/V.
// Block (qt, h, z): q rows [qt*64,+64), head h, KV cols [z*512,+512).
// ---------------------------------------------------------------------------
__global__ __launch_bounds__(256, 4) void attn_kernel(
    const short* __restrict__ qm, const short* __restrict__ km,
    const short* __restrict__ vT, const uint8_t* __restrict__ dist,
    const float* __restrict__ semb, unsigned short* __restrict__ po,
    float* __restrict__ pml) {
  int qt = blockIdx.x, h = blockIdx.y, z = blockIdx.z;
  int tid = threadIdx.x, wid = tid >> 6, lane = tid & 63;
  int c15 = lane & 15, g = lane >> 4;

  __shared__ __align__(16) char Ks[8192];    // [64 kv][8 chunk16B] swizzled
  __shared__ __align__(16) char Vs[8192];    // [64 dh][8 chunk16B] swizzled
  __shared__ __align__(16) uint8_t Ds[4096]; // [64 q][4 chunk16B]  swizzled
  __shared__ float semb_s[12];
  if (tid < 11) semb_s[tid] = semb[tid];

  int q0  = qt * 64;             // block's q base
  int wq0 = q0 + wid * 16;       // wave's q base
  int kvz = z * 512;

  // Q as MFMA B-operand: lane (g,c15) holds Q[wq0+c15][ks*32+g*8+j]
  short8 aq[2];
  #pragma unroll
  for (int ks = 0; ks < 2; ++ks)
    aq[ks] = *(const short8*)(qm + (size_t)(wq0 + c15) * 512 + h * 64 + ks * 32 + g * 8);

  // staging indices (this thread handles tile chunks i and i+256)
  int i  = tid;                         // 0..255
  int r0 = i >> 3,        c0 = (i & 7) ^ (r0 & 7);
  int r1 = (256 + i) >> 3, c1 = ((256 + i) & 7) ^ (r1 & 7);
  int dr = i >> 2,        dc = (i & 3) ^ (dr & 3);

  f32x4 o[4] = {};
  float m = -1e30f, l = 0.0f;

  for (int t = 0; t < 8; ++t) {
    int kv0 = kvz + t * 64;

    __syncthreads();   // all waves done reading previous tile
    // stage K (2), V (2), dist (1) -- linear LDS dest, pre-swizzled source
    gload_lds16(km + (size_t)(kv0 + r0) * 512 + h * 64 + c0 * 8, Ks + wid * 1024);
    gload_lds16(km + (size_t)(kv0 + r1) * 512 + h * 64 + c1 * 8, Ks + 4096 + wid * 1024);
    gload_lds16(vT + (size_t)(h * 64 + r0) * 2048 + kv0 + c0 * 8, Vs + wid * 1024);
    gload_lds16(vT + (size_t)(h * 64 + r1) * 2048 + kv0 + c1 * 8, Vs + 4096 + wid * 1024);
    gload_lds16(dist + (size_t)(q0 + dr) * 2048 + kv0 + dc * 16, Ds + wid * 1024);
    __syncthreads();   // staging complete (compiler drains vmcnt before barrier)

    // --- S^T = K Q^T (K frags from LDS) ---
    f32x4 sacc[4] = {};
    __builtin_amdgcn_s_setprio(1);
    #pragma unroll
    for (int nt = 0; nt < 4; ++nt) {
      int row = nt * 16 + c15;
      #pragma unroll
      for (int ks = 0; ks < 2; ++ks) {
        short8 bk = *(const short8*)(Ks + row * 128 + (((ks * 4 + g) ^ (row & 7)) * 16));
        sacc[nt] = __builtin_amdgcn_mfma_f32_16x16x32_bf16(bk, aq[ks], sacc[nt], 0, 0, 0);
      }
    }
    __builtin_amdgcn_s_setprio(0);

    // --- scale + spatial bias (dist from LDS); row max ---
    int drow = wid * 16 + c15;
    float rmax = -1e30f;
    #pragma unroll
    for (int nt = 0; nt < 4; ++nt) {
      uint32_t d32 = *(const uint32_t*)(Ds + drow * 64 + ((nt ^ (drow & 3)) * 16) + g * 4);
      #pragma unroll
      for (int r = 0; r < 4; ++r) {
        float s = sacc[nt][r] * 0.125f + semb_s[(d32 >> (8 * r)) & 0xFFu];
        sacc[nt][r] = s;
        rmax = fmaxf(rmax, s);
      }
    }
    rmax = fmaxf(rmax, __shfl_xor(rmax, 16));
    rmax = fmaxf(rmax, __shfl_xor(rmax, 32));

    // --- online softmax update (per-lane scalars, q = c15); exp in-place ---
    float mn = fmaxf(m, rmax);
    float pscale = __expf(m - mn);
    m = mn;
    float rsum = 0.0f;
    #pragma unroll
    for (int nt = 0; nt < 4; ++nt)
      #pragma unroll
      for (int r = 0; r < 4; ++r) {
        float p = __expf(sacc[nt][r] - m);
        sacc[nt][r] = p;
        rsum += p;
      }
    rsum += __shfl_xor(rsum, 16);
    rsum += __shfl_xor(rsum, 32);
    l = l * pscale + rsum;

    // O rescale: O rows are q=g*4+r -> broadcast pscale from lane (g*4+r)
    float psr[4];
    #pragma unroll
    for (int r = 0; r < 4; ++r) psr[r] = __shfl(pscale, g * 4 + r);
    #pragma unroll
    for (int dt = 0; dt < 4; ++dt)
      #pragma unroll
      for (int r = 0; r < 4; ++r)
        o[dt][r] *= psr[r];

    // --- P -> bf16 + exchange into PV A-frags (two scoped halves) ---
    int src_lo = c15 + (g & 1) * 32;
    int src_hi = src_lo + 16;
    int sel = g >> 1;
    short8 pa[2];
    {
      uint32_t p00 = cvtpk_bf16(sacc[0][0], sacc[0][1]);
      uint32_t p01 = cvtpk_bf16(sacc[0][2], sacc[0][3]);
      uint32_t p10 = cvtpk_bf16(sacc[1][0], sacc[1][1]);
      uint32_t p11 = cvtpk_bf16(sacc[1][2], sacc[1][3]);
      uint32_t a0 = (uint32_t)__shfl((int)p00, src_lo);
      uint32_t a1 = (uint32_t)__shfl((int)p01, src_lo);
      uint32_t a2 = (uint32_t)__shfl((int)p00, src_hi);
      uint32_t a3 = (uint32_t)__shfl((int)p01, src_hi);
      uint32_t b0 = (uint32_t)__shfl((int)p10, src_lo);
      uint32_t b1 = (uint32_t)__shfl((int)p11, src_lo);
      uint32_t b2 = (uint32_t)__shfl((int)p10, src_hi);
      uint32_t b3 = (uint32_t)__shfl((int)p11, src_hi);
      union { short8 s8; uint32_t u[4]; } up;
      up.u[0] = sel ? b0 : a0;
      up.u[1] = sel ? b1 : a1;
      up.u[2] = sel ? b2 : a2;
      up.u[3] = sel ? b3 : a3;
      pa[0] = up.s8;
    }
    {
      uint32_t p00 = cvtpk_bf16(sacc[2][0], sacc[2][1]);
      uint32_t p01 = cvtpk_bf16(sacc[2][2], sacc[2][3]);
      uint32_t p10 = cvtpk_bf16(sacc[3][0], sacc[3][1]);
      uint32_t p11 = cvtpk_bf16(sacc[3][2], sacc[3][3]);
      uint32_t a0 = (uint32_t)__shfl((int)p00, src_lo);
      uint32_t a1 = (uint32_t)__shfl((int)p01, src_lo);
      uint32_t a2 = (uint32_t)__shfl((int)p00, src_hi);
      uint32_t a3 = (uint32_t)__shfl((int)p01, src_hi);
      uint32_t b0 = (uint32_t)__shfl((int)p10, src_lo);
      uint32_t b1 = (uint32_t)__shfl((int)p11, src_lo);
      uint32_t b2 = (uint32_t)__shfl((int)p10, src_hi);
      uint32_t b3 = (uint32_t)__shfl((int)p11, src_hi);
      union { short8 s8; uint32_t u[4]; } up;
      up.u[0] = sel ? b0 : a0;
      up.u[1] = sel ? b1 : a1;
      up.u[2] = sel ? b2 : a2;
      up.u[3] = sel ? b3 : a3;
      pa[1] = up.s8;
    }

    // --- O += P V (V frags from LDS) ---
    __builtin_amdgcn_s_setprio(1);
    #pragma unroll
    for (int dt = 0; dt < 4; ++dt) {
      int row = dt * 16 + c15;
      #pragma unroll
      for (int ks = 0; ks < 2; ++ks) {
        short8 bv = *(const short8*)(Vs + row * 128 + (((ks * 4 + g) ^ (row & 7)) * 16));
        o[dt] = __builtin_amdgcn_mfma_f32_16x16x32_bf16(pa[ks], bv, o[dt], 0, 0, 0);
      }
    }
    __builtin_amdgcn_s_setprio(0);
  }

  // ---- write unnormalized partials (no intra-block combine needed) ----
  #pragma unroll
  for (int dt = 0; dt < 4; ++dt)
    #pragma unroll
    for (int r = 0; r < 4; ++r) {
      int q = wq0 + g * 4 + r;
      po[((size_t)z * 2048 + q) * 512 + h * 64 + dt * 16 + c15] = f2bf(o[dt][r]);
    }
  if (g == 0) {
    int q = wq0 + c15;
    pml[(((size_t)z * 2048 + q) * 8 + h) * 2]     = m;
    pml[(((size_t)z * 2048 + q) * 8 + h) * 2 + 1] = l;
  }
}

// ---------------------------------------------------------------------------
// Cross-chunk attention combine (Z=4): ctx = sum(O_z e_z) / sum(l_z e_z)
// ---------------------------------------------------------------------------
__global__ __launch_bounds__(256) void attn_combine_kernel(
    const unsigned short* __restrict__ po, const float* __restrict__ pml,
    unsigned short* __restrict__ ctx) {
  int q = blockIdx.x, tid = threadIdx.x;
  #pragma unroll
  for (int half = 0; half < 2; ++half) {
    int d = half * 256 + tid;
    int h = d >> 6;
    float mm[4], ll[4];
    float ms = -1e30f;
    #pragma unroll
    for (int zz = 0; zz < 4; ++zz) {
      mm[zz] = pml[(((size_t)zz * 2048 + q) * 8 + h) * 2];
      ll[zz] = pml[(((size_t)zz * 2048 + q) * 8 + h) * 2 + 1];
      ms = fmaxf(ms, mm[zz]);
    }
    float num = 0.0f, den = 0.0f;
    #pragma unroll
    for (int zz = 0; zz < 4; ++zz) {
      float e = __expf(mm[zz] - ms);
      num += bf2f(po[((size_t)zz * 2048 + q) * 512 + d]) * e;
      den += ll[zz] * e;
    }
    ctx[(size_t)q * 512 + d] = f2bf(num / den);
  }
}

// ---------------------------------------------------------------------------
// LayerNorm(a + sum of NP partials) row-wise; optional bf16 copy of output
// ---------------------------------------------------------------------------
template <int NP, bool WB>
__global__ __launch_bounds__(256) void ln_kernel(
    const float* __restrict__ a,
    const float* __restrict__ p0, const float* __restrict__ p1,
    const float* __restrict__ p2, const float* __restrict__ p3,
    const float* __restrict__ w, const float* __restrict__ bb,
    float* __restrict__ out, unsigned short* __restrict__ outb) {
  int row = blockIdx.x, tid = threadIdx.x;
  size_t base = (size_t)row * 512;
  float v0 = a[base + tid]       + p0[base + tid];
  float v1 = a[base + tid + 256] + p0[base + tid + 256];
  if (NP > 1) { v0 += p1[base + tid]; v1 += p1[base + tid + 256]; }
  if (NP > 2) { v0 += p2[base + tid]; v1 += p2[base + tid + 256]; }
  if (NP > 3) { v0 += p3[base + tid]; v1 += p3[base + tid + 256]; }
  float s = v0 + v1, q = v0 * v0 + v1 * v1;
  for (int o = 32; o > 0; o >>= 1) { s += __shfl_down(s, o); q += __shfl_down(q, o); }
  __shared__ float rs[4], rq[4], bc[2];
  int wid = tid >> 6, lane = tid & 63;
  if (lane == 0) { rs[wid] = s; rq[wid] = q; }
  __syncthreads();
  if (tid == 0) {
    float S = rs[0] + rs[1] + rs[2] + rs[3];
    float Q = rq[0] + rq[1] + rq[2] + rq[3];
    float mu = S * (1.0f / 512.0f);
    bc[0] = mu;
    bc[1] = Q * (1.0f / 512.0f) - mu * mu;
  }
  __syncthreads();
  float mu = bc[0], inv = rsqrtf(bc[1] + 1e-5f);
  float o0 = (v0 - mu) * inv * w[tid] + bb[tid];
  float o1 = (v1 - mu) * inv * w[tid + 256] + bb[tid + 256];
  out[base + tid] = o0;
  out[base + tid + 256] = o1;
  if (WB) {
    outb[base + tid] = f2bf(o0);
    outb[base + tid + 256] = f2bf(o1);
  }
}

// ---------------------------------------------------------------------------
extern "C" void kernel_launch(void* const* d_in, const int* in_sizes, int n_in,
                              void* d_out, int out_size, void* d_ws, size_t ws_size,
                              hipStream_t stream) {
  (void)in_sizes; (void)n_in; (void)out_size; (void)ws_size;
  const float* x    = (const float*)d_in[0];
  const float* adj  = (const float*)d_in[1];
  const float* semb = (const float*)d_in[2];
  const float* wq   = (const float*)d_in[3];
  const float* bq   = (const float*)d_in[4];
  const float* wk   = (const float*)d_in[5];
  const float* bk   = (const float*)d_in[6];
  const float* wv   = (const float*)d_in[7];
  const float* bv   = (const float*)d_in[8];
  const float* wo   = (const float*)d_in[9];
  const float* bo   = (const float*)d_in[10];
  const float* ln1w = (const float*)d_in[11];
  const float* ln1b = (const float*)d_in[12];
  const float* w1   = (const float*)d_in[13];
  const float* b1   = (const float*)d_in[14];
  const float* w2   = (const float*)d_in[15];
  const float* b2   = (const float*)d_in[16];
  const float* ln2w = (const float*)d_in[17];
  const float* ln2b = (const float*)d_in[18];
  float* out = (float*)d_out;
  char* ws = (char*)d_ws;

  uint32_t*       adjb = (uint32_t*)(ws + OFF_ADJB);
  uint8_t*        dist = (uint8_t*)(ws + OFF_DIST);
  unsigned short* xb   = (unsigned short*)(ws + OFF_XB);
  unsigned short* wqb  = (unsigned short*)(ws + OFF_WQB);
  unsigned short* wkb  = (unsigned short*)(ws + OFF_WKB);
  unsigned short* wvb  = (unsigned short*)(ws + OFF_WVB);
  unsigned short* wob  = (unsigned short*)(ws + OFF_WOB);
  unsigned short* w1b  = (unsigned short*)(ws + OFF_W1B);
  unsigned short* w2b  = (unsigned short*)(ws + OFF_W2B);
  unsigned short* qm   = (unsigned short*)(ws + OFF_QM);
  unsigned short* km   = (unsigned short*)(ws + OFF_KM);
  unsigned short* vT   = (unsigned short*)(ws + OFF_VT);
  unsigned short* ctx  = (unsigned short*)(ws + OFF_CTX);
  float*          atmp = (float*)(ws + OFF_ATMP);
  float*          h1   = (float*)(ws + OFF_H1);
  unsigned short* h1b  = (unsigned short*)(ws + OFF_H1B);
  unsigned short* mid  = (unsigned short*)(ws + OFF_MID);
  float*          ffn2 = (float*)(ws + OFF_FFN2);
  // reused (liveness-checked) regions:
  unsigned short* po   = (unsigned short*)(ws + OFF_MID); // attn partial O bf16 [4][2048][512] (dead before FFN1 writes mid)
  float* pml   = (float*)(ws + OFF_FFN2);   // attn partial ml f32 [4][2048][8][2] (dead before FFN2 writes)
  float* distf = (float*)(ws + OFF_DIST);   // split-K partial (dist dead after attn)
  float* qmf   = (float*)(ws + OFF_QM);     // split-K partial (spans qm+km, dead after attn)
  float* vtf   = (float*)(ws + OFF_VT);     // split-K partial (spans vT+ctx, dead after out-proj)

  // ---- dtype conversions (fused) ----
  cvt_all_kernel<<<4096, 256, 0, stream>>>(x, wq, wk, wv, wo, w1, w2,
                                           xb, wqb, wkb, wvb, wob, w1b, w2b);

  // ---- adjacency bitsets ----
  pack_adj_kernel<<<2048, 256, 0, stream>>>(adj, adjb);

  // ---- fused: BFS (blocks 0..2047) + QKV projection (blocks 2048..2815) ----
  bfs_qkv_kernel<<<2816, 256, 0, stream>>>(
      adjb, dist, (const short*)xb,
      (const short*)wqb, (const short*)wkb, (const short*)wvb,
      bq, bk, bv, qm, km, vT);

  // ---- attention (KV-split x4, LDS-staged shared K/V) + combine ----
  attn_kernel<<<dim3(32, 8, 4), 256, 0, stream>>>(
      (const short*)qm, (const short*)km, (const short*)vT, dist, semb, po, pml);
  attn_combine_kernel<<<2048, 256, 0, stream>>>(po, pml, ctx);

  // ---- output projection (split-K x2) ----
  gemm_kernel<1><<<dim3(32, 8, 2), 256, 0, stream>>>(
      (const short*)ctx, (const short*)wob, bo,
      atmp, distf, nullptr, nullptr, nullptr, 512, 256, 512);

  // ---- LN1 (x + atmp + distf) ----
  ln_kernel<2, true><<<2048, 256, 0, stream>>>(x, atmp, distf, nullptr, nullptr,
                                               ln1w, ln1b, h1, h1b);

  // ---- FFN1 (GELU -> bf16 mid) ----
  gemm_kernel<2><<<dim3(32, 32), 256, 0, stream>>>(
      (const short*)h1b, (const short*)w1b, b1,
      nullptr, nullptr, nullptr, nullptr, mid, 512, 512, 2048);

  // ---- FFN2 (split-K x4) ----
  gemm_kernel<1><<<dim3(32, 8, 4), 256, 0, stream>>>(
      (const short*)mid, (const short*)w2b, b2,
      ffn2, distf, qmf, vtf, nullptr, 2048, 512, 512);

  // ---- LN2 (h1 + 4 partials) -> output ----
  ln_kernel<4, false><<<2048, 256, 0, stream>>>(h1, ffn2, distf, qmf, vtf,
                                                ln2w, ln2b, out, nullptr);
}

// Round 13
// 131.098 us; speedup vs baseline: 1.1489x; 1.0828x over previous
//
#include <hip/hip_runtime.h>
#include <cstdint>
#include <cstddef>

// ---------------------------------------------------------------------------
// GraphTransformerLayer on MI355X (gfx950)
//  - Floyd-Warshall w/ clip(10)  ==  BFS truncated at depth 9 (bitset)
//    R13: DIRECTION-OPTIMIZING BFS. Top-down gather is L2-BW bound (1.07GB
//    @ 23TB/s = 67% of L2 ceiling). Bottom-up levels (check unvisited nodes'
//    in-edges vs frontier bitset) cut traffic ~4x. Needs bit-transposed adj.
//  - GEMMs: 64x64 tiles, split-K for N=512 GEMMs (partials summed in LN)
//  - Attention (R10): LDS-staged shared K/V flash structure; in-register
//    softmax (swapped QK^T); cross-z combine x4 on bf16 partials.
// ---------------------------------------------------------------------------

typedef __attribute__((ext_vector_type(8))) short short8;     // 8 x bf16 (4 VGPR)
typedef __attribute__((ext_vector_type(4))) float f32x4;      // MFMA C/D frag

#define N_NODES 2048
#define DMODEL  512
#define NHEAD   8
#define DHEAD   64
#define FFDIM   2048

// ---- workspace layout (bytes) ---------------------------------------------
#define OFF_ADJB   (0)                       // u32 [2048][64]        512 KB
#define OFF_DIST   (0x80000)                 // u8  [2048][2048]      4 MB  (later: f32 partial x1)
#define OFF_XB     (0x480000)                // bf16[2048][512]       2 MB
#define OFF_WQB    (0x680000)                // bf16[512][512]        512 KB
#define OFF_WKB    (0x700000)
#define OFF_WVB    (0x780000)
#define OFF_WOB    (0x800000)
#define OFF_W1B    (0x880000)                // bf16[2048][512]       2 MB
#define OFF_W2B    (0xA80000)                // bf16[512][2048]       2 MB
#define OFF_QM     (0xC80000)                // bf16[2048][512]       2 MB  (later: f32 partial x1 spans QM+KM)
#define OFF_KM     (0xE80000)                // bf16[2048][512]       2 MB
#define OFF_VT     (0x1080000)               // bf16[512][2048]       2 MB  (later: f32 partial x1 spans VT+CTX)
#define OFF_CTX    (0x1280000)               // bf16[2048][512]       2 MB
#define OFF_ATMP   (0x1480000)               // f32 [2048][512]       4 MB
#define OFF_H1     (0x1880000)               // f32 [2048][512]       4 MB
#define OFF_H1B    (0x1C80000)               // bf16[2048][512]       2 MB
#define OFF_MID    (0x1E80000)               // bf16[2048][2048]      8 MB
//   MID sublease: adjbT u32[2048][64] (512KB) during pack_adjT+bfs (dead after);
//                 attn partial O bf16 [4][2048][512] during attn (dead before FFN1)
#define OFF_FFN2   (0x2680000)               // f32 [2048][512]       4 MB  (earlier: attn partial ml f32 [4][2048][8][2])
// total 44.5 MB

__device__ __forceinline__ unsigned short f2bf(float f) {
  union { float f; unsigned u; } c; c.f = f;
  unsigned r = c.u + 0x7FFFu + ((c.u >> 16) & 1u);   // RNE
  return (unsigned short)(r >> 16);
}

__device__ __forceinline__ float bf2f(unsigned short u) {
  union { unsigned u; float f; } c; c.u = ((unsigned)u) << 16;
  return c.f;
}

__device__ __forceinline__ uint32_t cvtpk_bf16(float lo, float hi) {
  uint32_t r;
  asm("v_cvt_pk_bf16_f32 %0, %1, %2" : "=v"(r) : "v"(lo), "v"(hi));
  return r;
}

// global -> LDS async, 16B per lane. HW writes LDS at wave-uniform base + lane*16.
typedef const __attribute__((address_space(1))) unsigned int* as1_u32p;
typedef __attribute__((address_space(3))) unsigned int* as3_u32p;
__device__ __forceinline__ void gload_lds16(const void* g, void* l) {
  __builtin_amdgcn_global_load_lds((as1_u32p)g, (as3_u32p)l, 16, 0, 0);
}

// ---------------------------------------------------------------------------
// fused f32 -> bf16 conversion for all 7 arrays (4 elems/thread)
// ---------------------------------------------------------------------------
__global__ void cvt_all_kernel(const float* __restrict__ x,
                               const float* __restrict__ wq, const float* __restrict__ wk,
                               const float* __restrict__ wv, const float* __restrict__ wo,
                               const float* __restrict__ w1, const float* __restrict__ w2,
                               unsigned short* __restrict__ xb,
                               unsigned short* __restrict__ wqb, unsigned short* __restrict__ wkb,
                               unsigned short* __restrict__ wvb, unsigned short* __restrict__ wob,
                               unsigned short* __restrict__ w1b, unsigned short* __restrict__ w2b) {
  int i = blockIdx.x * 256 + threadIdx.x;       // 0 .. 1048575
  const float* src; unsigned short* dst; int off;
  if (i < 262144)      { src = x;  dst = xb;  off = i; }
  else if (i < 327680) { src = wq; dst = wqb; off = i - 262144; }
  else if (i < 393216) { src = wk; dst = wkb; off = i - 327680; }
  else if (i < 458752) { src = wv; dst = wvb; off = i - 393216; }
  else if (i < 524288) { src = wo; dst = wob; off = i - 458752; }
  else if (i < 786432) { src = w1; dst = w1b; off = i - 524288; }
  else                 { src = w2; dst = w2b; off = i - 786432; }
  float4 v = ((const float4*)src)[off];
  unsigned p0 = (unsigned)f2bf(v.x) | ((unsigned)f2bf(v.y) << 16);
  unsigned p1 = (unsigned)f2bf(v.z) | ((unsigned)f2bf(v.w) << 16);
  ((uint2*)dst)[off] = make_uint2(p0, p1);
}

// ---------------------------------------------------------------------------
// adj (f32 0/1) -> row bitsets, u32 [2048][64]
// ---------------------------------------------------------------------------
__global__ void pack_adj_kernel(const float* __restrict__ adj, uint32_t* __restrict__ adjb) {
  int i = blockIdx.x;
  int tid = threadIdx.x, wid = tid >> 6, lane = tid & 63;
  for (int it = 0; it < 8; ++it) {
    int jbase = it * 256 + wid * 64;
    int j = jbase + lane;
    unsigned long long m = __ballot(adj[(size_t)i * 2048 + j] > 0.0f);
    int w32 = jbase >> 5;
    if (lane == 0)  adjb[i * 64 + w32]     = (uint32_t)m;
    if (lane == 32) adjb[i * 64 + w32 + 1] = (uint32_t)(m >> 32);
  }
}

// ---------------------------------------------------------------------------
// adj (f32) -> TRANSPOSED row bitsets adjbT: adjbT[j][word iw] bit r = adj[iw*32+r][j]
// block (iw, j0/256); thread j accumulates 32 rows' column-j bits.
// ---------------------------------------------------------------------------
__global__ __launch_bounds__(256) void pack_adjT_kernel(const float* __restrict__ adj,
                                                        uint32_t* __restrict__ adjbT) {
  int iw = blockIdx.x;                 // 0..63
  int j  = blockIdx.y * 256 + threadIdx.x;
  uint32_t acc = 0;
  #pragma unroll
  for (int r = 0; r < 32; ++r)
    acc |= (adj[(size_t)(iw * 32 + r) * 2048 + j] > 0.0f ? 1u : 0u) << r;
  adjbT[(size_t)j * 64 + iw] = acc;
}

// ---------------------------------------------------------------------------
// Direction-optimizing BFS truncated at depth 9 -> dist u8 in [0,10].
// One block (4 waves) per source. State (front/reach, lane l owns word l)
// replicated per wave -> block-uniform decisions without barriers.
// Top-down level: compact frontier, gather out-rows (adjb), OR.   (R10 path)
// Bottom-up level (when cntU < cntF/2): compact unvisited, gather in-rows
// (adjbT), AND vs frontier bitset in LDS, ballot per node, atomicOr new bits.
// ---------------------------------------------------------------------------
__global__ __launch_bounds__(256) void bfs_kernel(const uint32_t* __restrict__ adjb,
                                                  const uint32_t* __restrict__ adjbT,
                                                  uint8_t* __restrict__ dist) {
  int i = blockIdx.x;
  int tid = threadIdx.x, wid = tid >> 6, lane = tid & 63;

  __shared__ uint16_t list_s[2112];
  __shared__ uint4 comb_v[4][64];
  __shared__ uint32_t wtot[4];
  __shared__ uint32_t fl_s[64];
  __shared__ uint32_t nf_s[64];
  const uint32_t* comb_u = (const uint32_t*)comb_v;

  uint32_t adjrow = adjb[i * 64 + lane];
  uint32_t diagm  = (lane == (i >> 5)) ? (1u << (i & 31)) : 0u;
  uint32_t front  = adjrow & ~diagm;          // exactly distance-1 nodes
  uint32_t reach  = front | diagm;
  uint32_t dp0 = front;
  uint32_t dp1 = ~(front | diagm);
  uint32_t dp2 = 0u;
  uint32_t dp3 = dp1;

  for (int t = 2; t <= 9; ++t) {
    // block-uniform popcounts (state replicated per wave)
    int cf = __popc(front), cu = __popc(~reach);
    #pragma unroll
    for (int o = 1; o < 64; o <<= 1) { cf += __shfl_xor(cf, o); cu += __shfl_xor(cu, o); }
    if (cf == 0) break;
    bool bottom_up = (cu < (cf >> 1));

    uint32_t nf;
    if (!bottom_up) {
      // ---------------- top-down (R10-proven) ----------------
      uint32_t fw = __shfl(front, wid * 16 + (lane >> 2));
      uint32_t fb = (fw >> ((lane & 3) * 8)) & 0xFFu;
      int cnt = __popc(fb);
      int scan = cnt;
      #pragma unroll
      for (int o = 1; o < 64; o <<= 1) {
        int u = __shfl_up(scan, o);
        if (lane >= o) scan += u;
      }
      if (lane == 63) wtot[wid] = (uint32_t)scan;
      __syncthreads();
      int w0 = (int)wtot[0], w1 = (int)wtot[1], w2 = (int)wtot[2], w3 = (int)wtot[3];
      int cnt_total = w0 + w1 + w2 + w3;
      int base0 = (wid > 0 ? w0 : 0) + (wid > 1 ? w1 : 0) + (wid > 2 ? w2 : 0);
      int off = base0 + scan - cnt;
      int nodebase = tid * 8;
      while (fb) {
        int b = __builtin_ctz(fb);
        fb &= fb - 1u;
        list_s[off++] = (uint16_t)(nodebase + b);
      }
      int padded = (cnt_total + 63) & ~63;
      for (int k = cnt_total + tid; k < padded; k += 256)
        list_s[k] = (uint16_t)i;             // source row: subset of reach
      __syncthreads();

      uint4 acc = make_uint4(0u, 0u, 0u, 0u);
      int wsub = (lane & 15) * 4;
      for (int base = wid * 16; base < padded; base += 64) {
        #pragma unroll
        for (int j = 0; j < 4; ++j) {
          int node = list_s[base + j * 4 + (lane >> 4)];
          uint4 v = *(const uint4*)(adjb + node * 64 + wsub);
          acc.x |= v.x; acc.y |= v.y; acc.z |= v.z; acc.w |= v.w;
        }
      }
      comb_v[wid][lane] = acc;
      __syncthreads();
      uint32_t orv = 0;
      int idx = (lane >> 2) * 4 + (lane & 3);
      #pragma unroll
      for (int w4 = 0; w4 < 4; ++w4)
        #pragma unroll
        for (int g = 0; g < 4; ++g)
          orv |= comb_u[w4 * 256 + g * 64 + idx];
      nf = orv & ~reach;
    } else {
      // ---------------- bottom-up ----------------
      uint32_t uv = ~reach;
      uint32_t fw = __shfl(uv, wid * 16 + (lane >> 2));
      uint32_t fb = (fw >> ((lane & 3) * 8)) & 0xFFu;
      int cnt = __popc(fb);
      int scan = cnt;
      #pragma unroll
      for (int o = 1; o < 64; o <<= 1) {
        int u = __shfl_up(scan, o);
        if (lane >= o) scan += u;
      }
      if (lane == 63) wtot[wid] = (uint32_t)scan;
      if (wid == 0) { fl_s[lane] = front; nf_s[lane] = 0u; }
      __syncthreads();
      int w0 = (int)wtot[0], w1 = (int)wtot[1], w2 = (int)wtot[2], w3 = (int)wtot[3];
      int cnt_total = w0 + w1 + w2 + w3;
      int base0 = (wid > 0 ? w0 : 0) + (wid > 1 ? w1 : 0) + (wid > 2 ? w2 : 0);
      int off = base0 + scan - cnt;
      int nodebase = tid * 8;
      while (fb) {
        int b = __builtin_ctz(fb);
        fb &= fb - 1u;
        list_s[off++] = (uint16_t)(nodebase + b);
      }
      int padded = (cnt_total + 63) & ~63;
      for (int k = cnt_total + tid; k < padded; k += 256)
        list_s[k] = (uint16_t)i;             // source is reached: filtered below
      __syncthreads();

      int wsub = (lane & 15) * 4;
      unsigned long long gm = 0xFFFFull << ((lane >> 4) * 16);
      for (int base = wid * 16; base < padded; base += 64) {
        #pragma unroll
        for (int j = 0; j < 4; ++j) {
          int node = list_s[base + j * 4 + (lane >> 4)];
          uint4 v = *(const uint4*)(adjbT + node * 64 + wsub);
          uint32_t loc = (v.x & fl_s[wsub]) | (v.y & fl_s[wsub + 1]) |
                         (v.z & fl_s[wsub + 2]) | (v.w & fl_s[wsub + 3]);
          unsigned long long b = __ballot(loc != 0u);
          if (((lane & 15) == 0) && (b & gm))
            atomicOr(&nf_s[node >> 5], 1u << (node & 31));
        }
      }
      __syncthreads();
      nf = nf_s[lane] & ~reach;
    }

    dp0 = (dp0 & ~nf) | ((t & 1) ? nf : 0u);
    dp1 = (dp1 & ~nf) | ((t & 2) ? nf : 0u);
    dp2 = (dp2 & ~nf) | ((t & 4) ? nf : 0u);
    dp3 = (dp3 & ~nf) | ((t & 8) ? nf : 0u);
    front = nf;
    reach |= nf;
    __syncthreads();                         // protect list_s/comb/nf for next level
  }

  uint32_t p0 = __shfl(dp0, wid * 16 + (lane >> 2));
  uint32_t p1 = __shfl(dp1, wid * 16 + (lane >> 2));
  uint32_t p2 = __shfl(dp2, wid * 16 + (lane >> 2));
  uint32_t p3 = __shfl(dp3, wid * 16 + (lane >> 2));
  int sh = (lane & 3) * 8;
  uint32_t lo = 0, hi = 0;
  #pragma unroll
  for (int j = 0; j < 4; ++j) {
    int bit = sh + j;
    uint32_t d = ((p0 >> bit) & 1u) | (((p1 >> bit) & 1u) << 1) |
                 (((p2 >> bit) & 1u) << 2) | (((p3 >> bit) & 1u) << 3);
    lo |= d << (8 * j);
  }
  #pragma unroll
  for (int j = 0; j < 4; ++j) {
    int bit = sh + 4 + j;
    uint32_t d = ((p0 >> bit) & 1u) | (((p1 >> bit) & 1u) << 1) |
                 (((p2 >> bit) & 1u) << 2) | (((p3 >> bit) & 1u) << 3);
    hi |= d << (8 * j);
  }
  ((uint2*)(dist + (size_t)i * 2048))[tid] = make_uint2(lo, hi);
}

// ---------------------------------------------------------------------------
// GEMM core: C[64,64] += A[64,kc] * W[64,kc]^T  (bf16 row-major, ld = K)
// ---------------------------------------------------------------------------
__device__ __forceinline__ void gemm_core64(const short* __restrict__ A,
                                            const short* __restrict__ W,
                                            int K, int kstart, int kc,
                                            int am0, int bn0,
                                            f32x4 acc[2][2], char* smem) {
  int tid = threadIdx.x, wid = tid >> 6, lane = tid & 63;
  int c15 = lane & 15, g = lane >> 4;
  int wm = wid >> 1, wn = wid & 1;
  char* As = smem;              // 8 KB
  char* Bs = smem + 8192;       // 8 KB

  for (int kt = kstart; kt < kstart + kc; kt += 64) {
    __syncthreads();   // previous tile's LDS reads done
    #pragma unroll
    for (int i = 0; i < 2; ++i) {
      int c   = i * 256 + tid;
      int row = c >> 3;
      int kg  = (c & 7) ^ (row & 7);
      gload_lds16(A + (size_t)(am0 + row) * K + kt + kg * 8,
                  As + i * 4096 + wid * 1024);
      gload_lds16(W + (size_t)(bn0 + row) * K + kt + kg * 8,
                  Bs + i * 4096 + wid * 1024);
    }
    __syncthreads();   // staging complete (implicit vmcnt(0))
    #pragma unroll
    for (int ks = 0; ks < 2; ++ks) {
      short8 af[2], bfr[2];
      #pragma unroll
      for (int mt = 0; mt < 2; ++mt) {
        int row   = wm * 32 + mt * 16 + c15;
        int chunk = (ks * 4 + g) ^ (row & 7);
        af[mt] = *(const short8*)(As + row * 128 + chunk * 16);
      }
      #pragma unroll
      for (int nt = 0; nt < 2; ++nt) {
        int row   = wn * 32 + nt * 16 + c15;
        int chunk = (ks * 4 + g) ^ (row & 7);
        bfr[nt] = *(const short8*)(Bs + row * 128 + chunk * 16);
      }
      #pragma unroll
      for (int mt = 0; mt < 2; ++mt)
        #pragma unroll
        for (int nt = 0; nt < 2; ++nt)
          acc[mt][nt] = __builtin_amdgcn_mfma_f32_16x16x32_bf16(af[mt], bfr[nt], acc[mt][nt], 0, 0, 0);
    }
  }
}

// ---------------------------------------------------------------------------
// QKV GEMM: q,k -> bf16 row-major; v -> bf16 transposed vT[d][n]
// ---------------------------------------------------------------------------
__global__ __launch_bounds__(256) void qkv_kernel(
    const short* __restrict__ A,
    const short* __restrict__ W0, const short* __restrict__ W1, const short* __restrict__ W2,
    const float* __restrict__ b0, const float* __restrict__ b1, const float* __restrict__ b2,
    unsigned short* __restrict__ outq, unsigned short* __restrict__ outk,
    unsigned short* __restrict__ outv) {
  __shared__ __align__(16) char smem[16384];
  int by = blockIdx.y;
  int region = by >> 3;
  const short* W    = (region == 0) ? W0 : (region == 1) ? W1 : W2;
  const float* bias = (region == 0) ? b0 : (region == 1) ? b1 : b2;
  int bn0 = (by & 7) * 64;
  int am0 = blockIdx.x * 64;

  f32x4 acc[2][2] = {};
  gemm_core64(A, W, 512, 0, 512, am0, bn0, acc, smem);

  int tid = threadIdx.x, wid = tid >> 6, lane = tid & 63;
  int c15 = lane & 15, g = lane >> 4;
  int wm = wid >> 1, wn = wid & 1;

  #pragma unroll
  for (int mt = 0; mt < 2; ++mt)
    #pragma unroll
    for (int nt = 0; nt < 2; ++nt)
      #pragma unroll
      for (int r = 0; r < 4; ++r) {
        int row = am0 + wm * 32 + mt * 16 + g * 4 + r;   // D: row=(lane>>4)*4+reg
        int col = bn0 + wn * 32 + nt * 16 + c15;         // D: col=lane&15
        float v = acc[mt][nt][r] + bias[col];
        if (region == 0)      outq[(size_t)row * 512 + col] = f2bf(v);
        else if (region == 1) outk[(size_t)row * 512 + col] = f2bf(v);
        else                  outv[(size_t)col * 2048 + row] = f2bf(v);   // vT[d][n]
      }
}

// MODE 1: f32 out (+bias iff z==0); split-K partial selected by blockIdx.z
// MODE 2: bf16 out + bias + exact GELU
template <int MODE>
__global__ __launch_bounds__(256) void gemm_kernel(
    const short* __restrict__ A,
    const short* __restrict__ W0,
    const float* __restrict__ b0,
    float* __restrict__ of0, float* __restrict__ of1,
    float* __restrict__ of2, float* __restrict__ of3,
    unsigned short* __restrict__ outb,
    int K, int kc, int ldo) {
  __shared__ __align__(16) char smem[16384];
  int by = blockIdx.y, z = blockIdx.z;
  int bn0 = by * 64;
  int am0 = blockIdx.x * 64;

  f32x4 acc[2][2] = {};
  gemm_core64(A, W0, K, z * kc, kc, am0, bn0, acc, smem);

  int tid = threadIdx.x, wid = tid >> 6, lane = tid & 63;
  int c15 = lane & 15, g = lane >> 4;
  int wm = wid >> 1, wn = wid & 1;
  float* of = (z == 0) ? of0 : (z == 1) ? of1 : (z == 2) ? of2 : of3;

  #pragma unroll
  for (int mt = 0; mt < 2; ++mt)
    #pragma unroll
    for (int nt = 0; nt < 2; ++nt)
      #pragma unroll
      for (int r = 0; r < 4; ++r) {
        int row = am0 + wm * 32 + mt * 16 + g * 4 + r;   // D: row=(lane>>4)*4+reg
        int col = bn0 + wn * 32 + nt * 16 + c15;         // D: col=lane&15
        if (MODE == 1) {
          float v = acc[mt][nt][r] + ((z == 0) ? b0[col] : 0.0f);
          of[(size_t)row * ldo + col] = v;
        } else {
          float v = acc[mt][nt][r] + b0[col];
          float gv = 0.5f * v * (1.0f + erff(v * 0.70710678118654752f));
          outb[(size_t)row * ldo + col] = f2bf(gv);
        }
      }
}

// ---------------------------------------------------------------------------
// Flash attention (R10): LDS-staged shared K/V.
// Block (qt, h, z): q rows [qt*64,+64), head h, KV cols [z*512,+512).
// ---------------------------------------------------------------------------
__global__ __launch_bounds__(256, 4) void attn_kernel(
    const short* __restrict__ qm, const short* __restrict__ km,
    const short* __restrict__ vT, const uint8_t* __restrict__ dist,
    const float* __restrict__ semb, unsigned short* __restrict__ po,
    float* __restrict__ pml) {
  int qt = blockIdx.x, h = blockIdx.y, z = blockIdx.z;
  int tid = threadIdx.x, wid = tid >> 6, lane = tid & 63;
  int c15 = lane & 15, g = lane >> 4;

  __shared__ __align__(16) char Ks[8192];    // [64 kv][8 chunk16B] swizzled
  __shared__ __align__(16) char Vs[8192];    // [64 dh][8 chunk16B] swizzled
  __shared__ __align__(16) uint8_t Ds[4096]; // [64 q][4 chunk16B]  swizzled
  __shared__ float semb_s[12];
  if (tid < 11) semb_s[tid] = semb[tid];

  int q0  = qt * 64;             // block's q base
  int wq0 = q0 + wid * 16;       // wave's q base
  int kvz = z * 512;

  // Q as MFMA B-operand: lane (g,c15) holds Q[wq0+c15][ks*32+g*8+j]
  short8 aq[2];
  #pragma unroll
  for (int ks = 0; ks < 2; ++ks)
    aq[ks] = *(const short8*)(qm + (size_t)(wq0 + c15) * 512 + h * 64 + ks * 32 + g * 8);

  // staging indices (this thread handles tile chunks i and i+256)
  int i  = tid;                         // 0..255
  int r0 = i >> 3,        c0 = (i & 7) ^ (r0 & 7);
  int r1 = (256 + i) >> 3, c1 = ((256 + i) & 7) ^ (r1 & 7);
  int dr = i >> 2,        dc = (i & 3) ^ (dr & 3);

  f32x4 o[4] = {};
  float m = -1e30f, l = 0.0f;

  for (int t = 0; t < 8; ++t) {
    int kv0 = kvz + t * 64;

    __syncthreads();   // all waves done reading previous tile
    // stage K (2), V (2), dist (1) -- linear LDS dest, pre-swizzled source
    gload_lds16(km + (size_t)(kv0 + r0) * 512 + h * 64 + c0 * 8, Ks + wid * 1024);
    gload_lds16(km + (size_t)(kv0 + r1) * 512 + h * 64 + c1 * 8, Ks + 4096 + wid * 1024);
    gload_lds16(vT + (size_t)(h * 64 + r0) * 2048 + kv0 + c0 * 8, Vs + wid * 1024);
    gload_lds16(vT + (size_t)(h * 64 + r1) * 2048 + kv0 + c1 * 8, Vs + 4096 + wid * 1024);
    gload_lds16(dist + (size_t)(q0 + dr) * 2048 + kv0 + dc * 16, Ds + wid * 1024);
    __syncthreads();   // staging complete (compiler drains vmcnt before barrier)

    // --- S^T = K Q^T (K frags from LDS) ---
    f32x4 sacc[4] = {};
    __builtin_amdgcn_s_setprio(1);
    #pragma unroll
    for (int nt = 0; nt < 4; ++nt) {
      int row = nt * 16 + c15;
      #pragma unroll
      for (int ks = 0; ks < 2; ++ks) {
        short8 bk = *(const short8*)(Ks + row * 128 + (((ks * 4 + g) ^ (row & 7)) * 16));
        sacc[nt] = __builtin_amdgcn_mfma_f32_16x16x32_bf16(bk, aq[ks], sacc[nt], 0, 0, 0);
      }
    }
    __builtin_amdgcn_s_setprio(0);

    // --- scale + spatial bias (dist from LDS); row max ---
    int drow = wid * 16 + c15;
    float rmax = -1e30f;
    #pragma unroll
    for (int nt = 0; nt < 4; ++nt) {
      uint32_t d32 = *(const uint32_t*)(Ds + drow * 64 + ((nt ^ (drow & 3)) * 16) + g * 4);
      #pragma unroll
      for (int r = 0; r < 4; ++r) {
        float s = sacc[nt][r] * 0.125f + semb_s[(d32 >> (8 * r)) & 0xFFu];
        sacc[nt][r] = s;
        rmax = fmaxf(rmax, s);
      }
    }
    rmax = fmaxf(rmax, __shfl_xor(rmax, 16));
    rmax = fmaxf(rmax, __shfl_xor(rmax, 32));

    // --- online softmax update (per-lane scalars, q = c15); exp in-place ---
    float mn = fmaxf(m, rmax);
    float pscale = __expf(m - mn);
    m = mn;
    float rsum = 0.0f;
    #pragma unroll
    for (int nt = 0; nt < 4; ++nt)
      #pragma unroll
      for (int r = 0; r < 4; ++r) {
        float p = __expf(sacc[nt][r] - m);
        sacc[nt][r] = p;
        rsum += p;
      }
    rsum += __shfl_xor(rsum, 16);
    rsum += __shfl_xor(rsum, 32);
    l = l * pscale + rsum;

    // O rescale: O rows are q=g*4+r -> broadcast pscale from lane (g*4+r)
    float psr[4];
    #pragma unroll
    for (int r = 0; r < 4; ++r) psr[r] = __shfl(pscale, g * 4 + r);
    #pragma unroll
    for (int dt = 0; dt < 4; ++dt)
      #pragma unroll
      for (int r = 0; r < 4; ++r)
        o[dt][r] *= psr[r];

    // --- P -> bf16 + exchange into PV A-frags (two scoped halves) ---
    int src_lo = c15 + (g & 1) * 32;
    int src_hi = src_lo + 16;
    int sel = g >> 1;
    short8 pa[2];
    {
      uint32_t p00 = cvtpk_bf16(sacc[0][0], sacc[0][1]);
      uint32_t p01 = cvtpk_bf16(sacc[0][2], sacc[0][3]);
      uint32_t p10 = cvtpk_bf16(sacc[1][0], sacc[1][1]);
      uint32_t p11 = cvtpk_bf16(sacc[1][2], sacc[1][3]);
      uint32_t a0 = (uint32_t)__shfl((int)p00, src_lo);
      uint32_t a1 = (uint32_t)__shfl((int)p01, src_lo);
      uint32_t a2 = (uint32_t)__shfl((int)p00, src_hi);
      uint32_t a3 = (uint32_t)__shfl((int)p01, src_hi);
      uint32_t b0 = (uint32_t)__shfl((int)p10, src_lo);
      uint32_t b1 = (uint32_t)__shfl((int)p11, src_lo);
      uint32_t b2 = (uint32_t)__shfl((int)p10, src_hi);
      uint32_t b3 = (uint32_t)__shfl((int)p11, src_hi);
      union { short8 s8; uint32_t u[4]; } up;
      up.u[0] = sel ? b0 : a0;
      up.u[1] = sel ? b1 : a1;
      up.u[2] = sel ? b2 : a2;
      up.u[3] = sel ? b3 : a3;
      pa[0] = up.s8;
    }
    {
      uint32_t p00 = cvtpk_bf16(sacc[2][0], sacc[2][1]);
      uint32_t p01 = cvtpk_bf16(sacc[2][2], sacc[2][3]);
      uint32_t p10 = cvtpk_bf16(sacc[3][0], sacc[3][1]);
      uint32_t p11 = cvtpk_bf16(sacc[3][2], sacc[3][3]);
      uint32_t a0 = (uint32_t)__shfl((int)p00, src_lo);
      uint32_t a1 = (uint32_t)__shfl((int)p01, src_lo);
      uint32_t a2 = (uint32_t)__shfl((int)p00, src_hi);
      uint32_t a3 = (uint32_t)__shfl((int)p01, src_hi);
      uint32_t b0 = (uint32_t)__shfl((int)p10, src_lo);
      uint32_t b1 = (uint32_t)__shfl((int)p11, src_lo);
      uint32_t b2 = (uint32_t)__shfl((int)p10, src_hi);
      uint32_t b3 = (uint32_t)__shfl((int)p11, src_hi);
      union { short8 s8; uint32_t u[4]; } up;
      up.u[0] = sel ? b0 : a0;
      up.u[1] = sel ? b1 : a1;
      up.u[2] = sel ? b2 : a2;
      up.u[3] = sel ? b3 : a3;
      pa[1] = up.s8;
    }

    // --- O += P V (V frags from LDS) ---
    __builtin_amdgcn_s_setprio(1);
    #pragma unroll
    for (int dt = 0; dt < 4; ++dt) {
      int row = dt * 16 + c15;
      #pragma unroll
      for (int ks = 0; ks < 2; ++ks) {
        short8 bv = *(const short8*)(Vs + row * 128 + (((ks * 4 + g) ^ (row & 7)) * 16));
        o[dt] = __builtin_amdgcn_mfma_f32_16x16x32_bf16(pa[ks], bv, o[dt], 0, 0, 0);
      }
    }
    __builtin_amdgcn_s_setprio(0);
  }

  // ---- write unnormalized partials (no intra-block combine needed) ----
  #pragma unroll
  for (int dt = 0; dt < 4; ++dt)
    #pragma unroll
    for (int r = 0; r < 4; ++r) {
      int q = wq0 + g * 4 + r;
      po[((size_t)z * 2048 + q) * 512 + h * 64 + dt * 16 + c15] = f2bf(o[dt][r]);
    }
  if (g == 0) {
    int q = wq0 + c15;
    pml[(((size_t)z * 2048 + q) * 8 + h) * 2]     = m;
    pml[(((size_t)z * 2048 + q) * 8 + h) * 2 + 1] = l;
  }
}

// ---------------------------------------------------------------------------
// Cross-chunk attention combine (Z=4): ctx = sum(O_z e_z) / sum(l_z e_z)
// ---------------------------------------------------------------------------
__global__ __launch_bounds__(256) void attn_combine_kernel(
    const unsigned short* __restrict__ po, const float* __restrict__ pml,
    unsigned short* __restrict__ ctx) {
  int q = blockIdx.x, tid = threadIdx.x;
  #pragma unroll
  for (int half = 0; half < 2; ++half) {
    int d = half * 256 + tid;
    int h = d >> 6;
    float mm[4], ll[4];
    float ms = -1e30f;
    #pragma unroll
    for (int zz = 0; zz < 4; ++zz) {
      mm[zz] = pml[(((size_t)zz * 2048 + q) * 8 + h) * 2];
      ll[zz] = pml[(((size_t)zz * 2048 + q) * 8 + h) * 2 + 1];
      ms = fmaxf(ms, mm[zz]);
    }
    float num = 0.0f, den = 0.0f;
    #pragma unroll
    for (int zz = 0; zz < 4; ++zz) {
      float e = __expf(mm[zz] - ms);
      num += bf2f(po[((size_t)zz * 2048 + q) * 512 + d]) * e;
      den += ll[zz] * e;
    }
    ctx[(size_t)q * 512 + d] = f2bf(num / den);
  }
}

// ---------------------------------------------------------------------------
// LayerNorm(a + sum of NP partials) row-wise; optional bf16 copy of output
// ---------------------------------------------------------------------------
template <int NP, bool WB>
__global__ __launch_bounds__(256) void ln_kernel(
    const float* __restrict__ a,
    const float* __restrict__ p0, const float* __restrict__ p1,
    const float* __restrict__ p2, const float* __restrict__ p3,
    const float* __restrict__ w, const float* __restrict__ bb,
    float* __restrict__ out, unsigned short* __restrict__ outb) {
  int row = blockIdx.x, tid = threadIdx.x;
  size_t base = (size_t)row * 512;
  float v0 = a[base + tid]       + p0[base + tid];
  float v1 = a[base + tid + 256] + p0[base + tid + 256];
  if (NP > 1) { v0 += p1[base + tid]; v1 += p1[base + tid + 256]; }
  if (NP > 2) { v0 += p2[base + tid]; v1 += p2[base + tid + 256]; }
  if (NP > 3) { v0 += p3[base + tid]; v1 += p3[base + tid + 256]; }
  float s = v0 + v1, q = v0 * v0 + v1 * v1;
  for (int o = 32; o > 0; o >>= 1) { s += __shfl_down(s, o); q += __shfl_down(q, o); }
  __shared__ float rs[4], rq[4], bc[2];
  int wid = tid >> 6, lane = tid & 63;
  if (lane == 0) { rs[wid] = s; rq[wid] = q; }
  __syncthreads();
  if (tid == 0) {
    float S = rs[0] + rs[1] + rs[2] + rs[3];
    float Q = rq[0] + rq[1] + rq[2] + rq[3];
    float mu = S * (1.0f / 512.0f);
    bc[0] = mu;
    bc[1] = Q * (1.0f / 512.0f) - mu * mu;
  }
  __syncthreads();
  float mu = bc[0], inv = rsqrtf(bc[1] + 1e-5f);
  float o0 = (v0 - mu) * inv * w[tid] + bb[tid];
  float o1 = (v1 - mu) * inv * w[tid + 256] + bb[tid + 256];
  out[base + tid] = o0;
  out[base + tid + 256] = o1;
  if (WB) {
    outb[base + tid] = f2bf(o0);
    outb[base + tid + 256] = f2bf(o1);
  }
}

// ---------------------------------------------------------------------------
extern "C" void kernel_launch(void* const* d_in, const int* in_sizes, int n_in,
                              void* d_out, int out_size, void* d_ws, size_t ws_size,
                              hipStream_t stream) {
  (void)in_sizes; (void)n_in; (void)out_size; (void)ws_size;
  const float* x    = (const float*)d_in[0];
  const float* adj  = (const float*)d_in[1];
  const float* semb = (const float*)d_in[2];
  const float* wq   = (const float*)d_in[3];
  const float* bq   = (const float*)d_in[4];
  const float* wk   = (const float*)d_in[5];
  const float* bk   = (const float*)d_in[6];
  const float* wv   = (const float*)d_in[7];
  const float* bv   = (const float*)d_in[8];
  const float* wo   = (const float*)d_in[9];
  const float* bo   = (const float*)d_in[10];
  const float* ln1w = (const float*)d_in[11];
  const float* ln1b = (const float*)d_in[12];
  const float* w1   = (const float*)d_in[13];
  const float* b1   = (const float*)d_in[14];
  const float* w2   = (const float*)d_in[15];
  const float* b2   = (const float*)d_in[16];
  const float* ln2w = (const float*)d_in[17];
  const float* ln2b = (const float*)d_in[18];
  float* out = (float*)d_out;
  char* ws = (char*)d_ws;

  uint32_t*       adjb = (uint32_t*)(ws + OFF_ADJB);
  uint8_t*        dist = (uint8_t*)(ws + OFF_DIST);
  unsigned short* xb   = (unsigned short*)(ws + OFF_XB);
  unsigned short* wqb  = (unsigned short*)(ws + OFF_WQB);
  unsigned short* wkb  = (unsigned short*)(ws + OFF_WKB);
  unsigned short* wvb  = (unsigned short*)(ws + OFF_WVB);
  unsigned short* wob  = (unsigned short*)(ws + OFF_WOB);
  unsigned short* w1b  = (unsigned short*)(ws + OFF_W1B);
  unsigned short* w2b  = (unsigned short*)(ws + OFF_W2B);
  unsigned short* qm   = (unsigned short*)(ws + OFF_QM);
  unsigned short* km   = (unsigned short*)(ws + OFF_KM);
  unsigned short* vT   = (unsigned short*)(ws + OFF_VT);
  unsigned short* ctx  = (unsigned short*)(ws + OFF_CTX);
  float*          atmp = (float*)(ws + OFF_ATMP);
  float*          h1   = (float*)(ws + OFF_H1);
  unsigned short* h1b  = (unsigned short*)(ws + OFF_H1B);
  unsigned short* mid  = (unsigned short*)(ws + OFF_MID);
  float*          ffn2 = (float*)(ws + OFF_FFN2);
  // reused (liveness-checked) regions:
  uint32_t* adjbT = (uint32_t*)(ws + OFF_MID);            // 512KB during pack_adjT+bfs (dead after bfs)
  unsigned short* po   = (unsigned short*)(ws + OFF_MID); // attn partial O bf16 [4][2048][512] (written after bfs done)
  float* pml   = (float*)(ws + OFF_FFN2);   // attn partial ml f32 [4][2048][8][2] (dead before FFN2 writes)
  float* distf = (float*)(ws + OFF_DIST);   // split-K partial (dist dead after attn)
  float* qmf   = (float*)(ws + OFF_QM);     // split-K partial (spans qm+km, dead after attn)
  float* vtf   = (float*)(ws + OFF_VT);     // split-K partial (spans vT+ctx, dead after out-proj)

  // ---- dtype conversions (fused) ----
  cvt_all_kernel<<<4096, 256, 0, stream>>>(x, wq, wk, wv, wo, w1, w2,
                                           xb, wqb, wkb, wvb, wob, w1b, w2b);

  // ---- adjacency bitsets (forward + transposed) ----
  pack_adj_kernel<<<2048, 256, 0, stream>>>(adj, adjb);
  pack_adjT_kernel<<<dim3(64, 8), 256, 0, stream>>>(adj, adjbT);

  // ---- direction-optimizing BFS ----
  bfs_kernel<<<2048, 256, 0, stream>>>(adjb, adjbT, dist);

  // ---- QKV projection (q,k row-major; v transposed) ----
  qkv_kernel<<<dim3(32, 24), 256, 0, stream>>>(
      (const short*)xb, (const short*)wqb, (const short*)wkb, (const short*)wvb,
      bq, bk, bv, qm, km, vT);

  // ---- attention (KV-split x4, LDS-staged shared K/V) + combine ----
  attn_kernel<<<dim3(32, 8, 4), 256, 0, stream>>>(
      (const short*)qm, (const short*)km, (const short*)vT, dist, semb, po, pml);
  attn_combine_kernel<<<2048, 256, 0, stream>>>(po, pml, ctx);

  // ---- output projection (split-K x2) ----
  gemm_kernel<1><<<dim3(32, 8, 2), 256, 0, stream>>>(
      (const short*)ctx, (const short*)wob, bo,
      atmp, distf, nullptr, nullptr, nullptr, 512, 256, 512);

  // ---- LN1 (x + atmp + distf) ----
  ln_kernel<2, true><<<2048, 256, 0, stream>>>(x, atmp, distf, nullptr, nullptr,
                                               ln1w, ln1b, h1, h1b);

  // ---- FFN1 (GELU -> bf16 mid) ----
  gemm_kernel<2><<<dim3(32, 32), 256, 0, stream>>>(
      (const short*)h1b, (const short*)w1b, b1,
      nullptr, nullptr, nullptr, nullptr, mid, 512, 512, 2048);

  // ---- FFN2 (split-K x4) ----
  gemm_kernel<1><<<dim3(32, 8, 4), 256, 0, stream>>>(
      (const short*)mid, (const short*)w2b, b2,
      ffn2, distf, qmf, vtf, nullptr, 2048, 512, 512);

  // ---- LN2 (h1 + 4 partials) -> output ----
  ln_kernel<4, false><<<2048, 256, 0, stream>>>(h1, ffn2, distf, qmf, vtf,
                                                ln2w, ln2b, out, nullptr);
}